// Round 14
// baseline (1210.189 us; speedup 1.0000x reference)
//
#include <hip/hip_runtime.h>
#include <cstdint>

#define NB   16
#define LQN  300
#define DM   256
#define NH   8
#define DH   32
#define NLV  3
#define DFFN 1024
#define NLAY 6
#define TT   7168
#define MROW (NB*LQN)   // 4800
#define SROW (NB*TT)    // 114688
#define VAL8_STRIDE 29360128L   // SROW*256 bytes per layer

typedef __attribute__((ext_vector_type(8))) short bf16x8;
typedef __attribute__((ext_vector_type(4))) float f32x4;

__device__ __forceinline__ float bf2f(short u) {
  unsigned x = ((unsigned)(unsigned short)u) << 16;
  return __builtin_bit_cast(float, x);
}
__device__ __forceinline__ short f2bf(float f) {
  unsigned u = __builtin_bit_cast(unsigned, f);
  u += 0x7fffu + ((u >> 16) & 1u);   // RNE
  return (short)(u >> 16);
}
// ---- manual fp8 e4m3fn encode/decode (no builtin dependency) ----
__device__ __forceinline__ unsigned f2fp8(float f) {
  const unsigned sgn = (__builtin_bit_cast(unsigned, f) >> 31) << 7;
  float a = fminf(fabsf(f), 448.0f);
  unsigned x = __builtin_bit_cast(unsigned, a);
  const int ex = (int)(x >> 23) - 127;
  unsigned enc;
  if (ex >= -6) {
    x += 0x7FFFFu + ((x >> 20) & 1u);          // RNE into 3-bit mantissa
    enc = (((x >> 23) - 120u) << 3) | ((x >> 20) & 7u);
  } else {
    enc = (unsigned)(int)__builtin_rintf(a * 512.0f);   // subnormal (and 2^-6 boundary)
  }
  return sgn | enc;
}
__device__ __forceinline__ float fp82f(unsigned v) {
  const unsigned e = (v >> 3) & 15u, m = v & 7u;
  float r;
  if (e == 0) r = (float)m * 0.001953125f;     // m * 2^-9
  else r = __builtin_bit_cast(float, ((e + 120u) << 23) | (m << 20));
  return (v & 0x80u) ? -r : r;
}
__device__ __forceinline__ void load_lds16(const void* g, void* l) {
  __builtin_amdgcn_global_load_lds(
      (const __attribute__((address_space(1))) unsigned int*)g,
      (__attribute__((address_space(3))) unsigned int*)l, 16, 0, 0);
}
#define MFMA(a,b,c) __builtin_amdgcn_mfma_f32_16x16x32_bf16((a),(b),(c),0,0,0)

// ---------------- weight + src fp32->bf16 conversion ----------------
struct CvtPtrs { const float* p[13]; };

__global__ __launch_bounds__(256)
void cvt_all_kernel(CvtPtrs ptrs, short* __restrict__ dst)
{
  const long gid = (long)blockIdx.x*256 + threadIdx.x;  // float4 units
  const long cums[14] = {0,32768,49152,65536,81920,376832,475136,512000,
                         548864,647168,745472,1138688,1531904,8871936};
  int s = 0;
  #pragma unroll
  for (int i = 1; i < 13; ++i) s += (gid >= cums[i]) ? 1 : 0;
  const long rel = gid - cums[s];
  const float4 v = ((const float4*)ptrs.p[s])[rel];
  long dstIdx = gid;
  if (s == 6) { const long l = rel/6144, w = rel%6144; dstIdx = 475136 + l*12288 + w; }
  else if (s == 7) { const long l = rel/6144, w = rel%6144; dstIdx = 475136 + l*12288 + 6144 + w; }
  ((short4*)dst)[dstIdx] = make_short4(f2bf(v.x), f2bf(v.y), f2bf(v.z), f2bf(v.w));
}

#define VLS 264   // padded LDS row stride (shorts)

// ---------------- val projection: BC=128 streaming GEMM -> fp8 output ----------------
__global__ __launch_bounds__(512, 2)
void val_gemm(const short* __restrict__ srcbf, const short* __restrict__ Bw,
              const float* __restrict__ bias, unsigned char* __restrict__ C8,
              const unsigned char* __restrict__ rowmask)
{
  __shared__ short Bs[128*VLS];   // 67,584 B
  const int tid = threadIdx.x, wid = tid >> 6, lane = tid & 63;
  const int fr = lane & 15, fq = lane >> 4;
  const int coff = blockIdx.y * 128;

  for (int t = tid; t < 4096; t += 512) {
    const int row = t >> 5, ch = t & 31;
    const int chs = ch ^ ((row >> 4) & 7);
    *(bf16x8*)&Bs[row*VLS + chs*8] = *(const bf16x8*)(Bw + (long)(coff + row)*256 + ch*8);
  }
  __syncthreads();

  float bv[8];
  #pragma unroll
  for (int j = 0; j < 2; ++j)
    *(float4*)&bv[j*4] = *(const float4*)(bias + coff + fr*8 + j*4);

  const int rbase = (blockIdx.x*8 + wid) * 32;   // 448*8 = 3584 = SROW/32

  bf16x8 ac0, ac1, an0, an1;
  ac0 = *(const bf16x8*)(srcbf + (long)(rbase + fr)*256 + fq*8);
  ac1 = *(const bf16x8*)(srcbf + (long)(rbase + 16 + fr)*256 + fq*8);

  f32x4 acc[2][8] = {};
  #pragma unroll
  for (int ks = 0; ks < 8; ++ks) {
    if (ks < 7) {
      an0 = *(const bf16x8*)(srcbf + (long)(rbase + fr)*256 + (ks+1)*32 + fq*8);
      an1 = *(const bf16x8*)(srcbf + (long)(rbase + 16 + fr)*256 + (ks+1)*32 + fq*8);
    }
    #pragma unroll
    for (int nt = 0; nt < 8; ++nt) {
      const int row = fr*8 + nt;
      const bf16x8 b = *(const bf16x8*)&Bs[row*VLS + (((ks*4 + fq) ^ ((row >> 4) & 7)))*8];
      acc[0][nt] = MFMA(ac0, b, acc[0][nt]);
      acc[1][nt] = MFMA(ac1, b, acc[1][nt]);
    }
    if (ks < 7) { ac0 = an0; ac1 = an1; }
  }

  #pragma unroll
  for (int h = 0; h < 2; ++h) {
    #pragma unroll
    for (int r = 0; r < 4; ++r) {
      const int grow = rbase + h*16 + fq*4 + r;
      const float msc = rowmask[grow] ? 0.0f : 1.0f;
      unsigned w0 = 0, w1 = 0;
      #pragma unroll
      for (int j = 0; j < 4; ++j) {
        w0 |= f2fp8((acc[h][j][r]   + bv[j])   * msc) << (j*8);
        w1 |= f2fp8((acc[h][4+j][r] + bv[4+j]) * msc) << (j*8);
      }
      uint2 o; o.x = w0; o.y = w1;
      *(uint2*)(C8 + (long)grow*256 + coff + fr*8) = o;
    }
  }
}

// ---------------- GEMM 64x64 tile, A[M,K] @ B[N,K]^T + bias (R3-proven) ----------------
// EPI: 0 plain, 1 relu->Cb, 2 qpos, 4 two-bias->Cf
template<int EPI>
__global__ __launch_bounds__(256)
void gemm64(const short* __restrict__ A, const short* __restrict__ B,
            const float* __restrict__ bias, const float* __restrict__ bias2,
            float* __restrict__ Cf, short* __restrict__ Cb, short* __restrict__ Cb2,
            int M, int N, int K, int ldc,
            const float* __restrict__ rawq, const float* __restrict__ resid)
{
  __shared__ short As[2][64*64];
  __shared__ short Bs[2][64*64];
  const int tid = threadIdx.x, wid = tid >> 6, lane = tid & 63;
  const int wr = wid >> 1, wc = wid & 1;
  const int fr = lane & 15, fq = lane >> 4;
  const int bm = blockIdx.x, bn = blockIdx.y;
  const int lrow = lane >> 3;
  const int schk = ((lane & 7) ^ lrow) * 8;
  const int nk = K >> 6;

  f32x4 acc[2][2] = {};

  auto stg = [&](int kt, int bsel) {
    const int k0 = kt << 6;
    #pragma unroll
    for (int i = 0; i < 2; ++i) {
      const int rr = wid*16 + i*8 + lrow;
      load_lds16(A + (long)(bm*64 + rr)*K + k0 + schk, &As[bsel][(wid*16 + i*8)*64]);
      load_lds16(B + (long)(bn*64 + rr)*K + k0 + schk, &Bs[bsel][(wid*16 + i*8)*64]);
    }
  };

  stg(0, 0);
  for (int t = 0; t < nk; ++t) {
    const int cur = t & 1;
    if (t + 1 < nk) {
      stg(t + 1, cur ^ 1);
      asm volatile("s_waitcnt vmcnt(4)" ::: "memory");
    } else {
      asm volatile("s_waitcnt vmcnt(0)" ::: "memory");
    }
    __builtin_amdgcn_s_barrier();
    __builtin_amdgcn_sched_barrier(0);
    #pragma unroll
    for (int kk = 0; kk < 64; kk += 32) {
      bf16x8 af[2], bv[2];
      #pragma unroll
      for (int mi = 0; mi < 2; ++mi)
        af[mi] = *(const bf16x8*)&As[cur][(wr*32 + mi*16 + fr)*64 + (((kk>>3)+fq) ^ (fr&7))*8];
      #pragma unroll
      for (int ni = 0; ni < 2; ++ni)
        bv[ni] = *(const bf16x8*)&Bs[cur][(wc*32 + ni*16 + fr)*64 + (((kk>>3)+fq) ^ (fr&7))*8];
      #pragma unroll
      for (int mi = 0; mi < 2; ++mi)
        #pragma unroll
        for (int ni = 0; ni < 2; ++ni)
          acc[mi][ni] = MFMA(af[mi], bv[ni], acc[mi][ni]);
    }
    __builtin_amdgcn_s_barrier();
  }

  #pragma unroll
  for (int mi = 0; mi < 2; ++mi) {
    #pragma unroll
    for (int r = 0; r < 4; ++r) {
      const int grow = bm*64 + wr*32 + mi*16 + fq*4 + r;
      #pragma unroll
      for (int ni = 0; ni < 2; ++ni) {
        const int gcol = bn*64 + wc*32 + ni*16 + fr;
        float v = acc[mi][ni][r];
        if (EPI == 4) v += (gcol < 96) ? bias[gcol] : bias2[gcol-96];
        else v += bias[gcol];
        const long off = (long)grow*ldc + gcol;
        if (EPI == 0) {
          if (Cf) Cf[off] = v;
          if (Cb) Cb[off] = f2bf(v);
        } else if (EPI == 1) {
          Cb[off] = f2bf(fmaxf(v, 0.0f));
        } else if (EPI == 2) {
          const float qp = v * rawq[off];
          Cf[off] = qp;
          Cb[off] = f2bf(resid[off] + qp);
        } else if (EPI == 4) {
          Cf[off] = v;
        }
      }
    }
  }
}

// ---------------- out = tgt (f32 + bf16 copies) ----------------
__global__ __launch_bounds__(256)
void ew0_kernel(const float* __restrict__ tgt, float* __restrict__ out, short* __restrict__ outbf)
{
  const long i = (long)blockIdx.x*256 + threadIdx.x;
  const float4 v = ((const float4*)tgt)[i];
  ((float4*)out)[i] = v;
  ((short4*)outbf)[i] = make_short4(f2bf(v.x), f2bf(v.y), f2bf(v.z), f2bf(v.w));
}

// ---------------- ref / ref_in / sine embedding ----------------
__global__ __launch_bounds__(256)
void init_ref_kernel(const float* __restrict__ seg, const float* __restrict__ dur,
                     const float* __restrict__ valid,
                     short* __restrict__ sinebf, float* __restrict__ refin)
{
  const int m = blockIdx.x;
  const int n = m / LQN;
  const int t = threadIdx.x;
  const float c = seg[(long)m*2 + 0];
  const float w = __expf(seg[(long)m*2 + 1]);
  const float e = (float)(t & ~1) * (1.0f/256.0f);
  const float invdim = __expf(-e * 9.2103403719761836f);
  const float twopi = 6.2831853071795864f;
  const float a0 = c * twopi * invdim;
  const float a1 = w * twopi * invdim;
  const float v0 = (t & 1) ? cosf(a0) : sinf(a0);
  const float v1 = (t & 1) ? cosf(a1) : sinf(a1);
  sinebf[(long)m*512 + t]       = f2bf(v0);
  sinebf[(long)m*512 + 256 + t] = f2bf(v1);
  if (t < 6) {
    const int l = t >> 1, cc = t & 1;
    const float rv = cc ? w : c;
    refin[(long)m*6 + l*2 + cc] = rv / dur[n] * valid[n*NLV + l];
  }
}

// ---------------- MFMA attention ----------------
#define KPAD 320
#define KSTR 40
#define VSTR 328
#define PSTR 328

__global__ __launch_bounds__(256)
void attn_mfma(const short* __restrict__ qk, const short* __restrict__ vv,
               short* __restrict__ outb)
{
  __shared__ short Kl[KPAD*KSTR];
  __shared__ short Vt[DH*VSTR];
  __shared__ short Pl[4][16*PSTR];
  const int b = blockIdx.x;
  const int half = b & 1, h = (b >> 1) & 7, n = b >> 4;
  const int tid = threadIdx.x, wid = tid >> 6, lane = tid & 63;
  const int fr = lane & 15, fq = lane >> 4;

  const short* qkn = qk + (long)n*LQN*512;
  const short* vn  = vv + (long)n*LQN*256;

  for (int t = tid; t < KPAD*4; t += 256) {
    const int r = t >> 2, c = t & 3;
    bf16x8 kv = {}, vw = {};
    if (r < LQN) {
      kv = *(const bf16x8*)(qkn + (long)r*512 + 256 + h*32 + c*8);
      vw = *(const bf16x8*)(vn  + (long)r*256 + h*32 + c*8);
    }
    *(bf16x8*)&Kl[r*KSTR + c*8] = kv;
    #pragma unroll
    for (int j = 0; j < 8; ++j) Vt[(c*8+j)*VSTR + r] = vw[j];
  }
  for (int t = tid; t < 4*16*24; t += 256) {
    const int w = t / (16*24), rr = (t / 24) & 15, cc = t % 24;
    Pl[w][rr*PSTR + 304 + cc] = 0;
  }
  __syncthreads();

  const int tlo = half ? 10 : 0, thi = half ? 19 : 10;
  const float scl2 = 0.17677669529663687f * 1.4426950408889634f;

  for (int qt = tlo + wid; qt < thi; qt += 4) {
    const int q0 = qt * 16;
    const int qrow = min(q0 + fr, LQN-1);
    const bf16x8 qf = *(const bf16x8*)(qkn + (long)qrow*512 + h*32 + fq*8);
    f32x4 s[19];
    #pragma unroll
    for (int t = 0; t < 19; ++t) {
      const bf16x8 kf = *(const bf16x8*)&Kl[(t*16+fr)*KSTR + fq*8];
      s[t] = MFMA(qf, kf, ((f32x4){0.f,0.f,0.f,0.f}));
    }
    float mx[4] = {-3e38f,-3e38f,-3e38f,-3e38f};
    #pragma unroll
    for (int t = 0; t < 19; ++t) {
      const bool valid = (t < 18) || (fr < 12);
      #pragma unroll
      for (int r = 0; r < 4; ++r) if (valid) mx[r] = fmaxf(mx[r], s[t][r]);
    }
    #pragma unroll
    for (int r = 0; r < 4; ++r) {
      #pragma unroll
      for (int o = 1; o < 16; o <<= 1) mx[r] = fmaxf(mx[r], __shfl_xor(mx[r], o));
      mx[r] *= scl2;
    }
    float l[4] = {0.f,0.f,0.f,0.f};
    #pragma unroll
    for (int t = 0; t < 19; ++t) {
      const bool valid = (t < 18) || (fr < 12);
      #pragma unroll
      for (int r = 0; r < 4; ++r) {
        const float p = valid ? exp2f(s[t][r]*scl2 - mx[r]) : 0.0f;
        l[r] += p;
        Pl[wid][(fq*4+r)*PSTR + t*16 + fr] = f2bf(p);
      }
    }
    #pragma unroll
    for (int r = 0; r < 4; ++r) {
      #pragma unroll
      for (int o = 1; o < 16; o <<= 1) l[r] += __shfl_xor(l[r], o);
    }
    f32x4 o0 = {}, o1 = {};
    #pragma unroll
    for (int ck = 0; ck < 10; ++ck) {
      const bf16x8 pf = *(const bf16x8*)&Pl[wid][fr*PSTR + ck*32 + fq*8];
      const bf16x8 v0 = *(const bf16x8*)&Vt[fr*VSTR + ck*32 + fq*8];
      const bf16x8 v1 = *(const bf16x8*)&Vt[(16+fr)*VSTR + ck*32 + fq*8];
      o0 = MFMA(pf, v0, o0);
      o1 = MFMA(pf, v1, o1);
    }
    #pragma unroll
    for (int r = 0; r < 4; ++r) {
      const int qq = q0 + fq*4 + r;
      if (qq < LQN) {
        const float inv = 1.0f / l[r];
        outb[((long)(n*LQN+qq))*256 + h*32 + fr]      = f2bf(o0[r]*inv);
        outb[((long)(n*LQN+qq))*256 + h*32 + 16 + fr] = f2bf(o1[r]*inv);
      }
    }
  }
}

// ---------------- residual + LayerNorm (+ optional caq = y+qpos) ----------------
__global__ __launch_bounds__(256)
void ln_kernel(const float* __restrict__ resid, const float* __restrict__ delta,
               const float* __restrict__ g, const float* __restrict__ b,
               float* __restrict__ of, short* __restrict__ ob,
               const float* __restrict__ qpos, short* __restrict__ caqb)
{
  const int m = blockIdx.x, c = threadIdx.x;
  const long idx = (long)m*DM + c;
  const float x = resid[idx] + delta[idx];
  float s = x, s2 = x*x;
  #pragma unroll
  for (int o = 1; o < 64; o <<= 1) { s += __shfl_xor(s, o); s2 += __shfl_xor(s2, o); }
  __shared__ float rs[4], rs2[4];
  const int w = c >> 6;
  if ((c & 63) == 0) { rs[w] = s; rs2[w] = s2; }
  __syncthreads();
  s  = rs[0]+rs[1]+rs[2]+rs[3];
  s2 = rs2[0]+rs2[1]+rs2[2]+rs2[3];
  const float mean = s * (1.0f/DM);
  const float var  = s2 * (1.0f/DM) - mean*mean;
  const float y = (x - mean) * rsqrtf(var + 1e-5f) * g[c] + b[c];
  of[idx] = y;
  if (ob) ob[idx] = f2bf(y);
  if (qpos) caqb[idx] = f2bf(y + qpos[idx]);
}

// ---------------- sampling: fused prep (softmax+bilinear) + gather-MAC, fp8 val ----------------
__global__ __launch_bounds__(256)
void sample_kernel(const unsigned char* __restrict__ val8,
                   const float* __restrict__ offaw, const float* __restrict__ refin,
                   const int* __restrict__ tlens, const int* __restrict__ lstart,
                   short* __restrict__ cab)
{
  const int m = blockIdx.x;
  const int n = m / LQN;
  const int tid = threadIdx.x;
  __shared__ int2  lI[96];
  __shared__ float2 lW[96];
  if ((tid & 31) == 0) {
    const int h = tid >> 5;
    const float* row = offaw + (long)m*192;
    float aw[12];
    float mx = -1e30f;
    #pragma unroll
    for (int lp = 0; lp < 12; ++lp) { aw[lp] = row[96 + h*12 + lp]; mx = fmaxf(mx, aw[lp]); }
    float sum = 0.0f;
    #pragma unroll
    for (int lp = 0; lp < 12; ++lp) { aw[lp] = __expf(aw[lp]-mx); sum += aw[lp]; }
    const float invs = 1.0f / sum;
    #pragma unroll
    for (int lp = 0; lp < 12; ++lp) {
      const int l = lp >> 2;
      const int tli = tlens[l];
      const float off = row[h*12 + lp];
      const float loc = refin[(long)m*6 + l*2] + off * 0.25f * refin[(long)m*6 + l*2 + 1] * 0.5f;
      const float x = loc * (float)tli - 0.5f;
      const float x0f = floorf(x);
      const float f = x - x0f;
      const int x0 = (int)x0f;
      const int i0 = lstart[l] + min(max(x0,   0), tli-1);
      const int i1 = lstart[l] + min(max(x0+1, 0), tli-1);
      const float wgt = aw[lp]*invs;
      const float w0 = (x0   >= 0 && x0   < tli) ? wgt*(1.0f-f) : 0.0f;
      const float w1 = (x0+1 >= 0 && x0+1 < tli) ? wgt*f        : 0.0f;
      lI[h*12 + lp] = make_int2(i0, i1);
      lW[h*12 + lp] = make_float2(w0, w1);
    }
  }
  __syncthreads();
  const int h = tid >> 5;
  const unsigned char* vb = val8 + (long)n*TT*256;
  float acc = 0.0f;
  #pragma unroll
  for (int lp = 0; lp < 12; ++lp) {
    const int e = h*12 + lp;
    const int2 ii = lI[e];
    const float2 ww = lW[e];
    acc += ww.x * fp82f(vb[(long)ii.x*256 + tid]) + ww.y * fp82f(vb[(long)ii.y*256 + tid]);
  }
  cab[(long)m*DM + tid] = f2bf(acc);
}

// ---------------- host side ----------------
static inline void g64(hipStream_t st, int epi, const short* A, const short* B,
                       const float* bias, const float* bias2,
                       float* Cf, short* Cb, short* Cb2,
                       int M, int N, int K, int ldc,
                       const float* rawq = nullptr, const float* resid = nullptr)
{
  dim3 g(M/64, N/64), blk(256);
  switch (epi) {
    case 0: gemm64<0><<<g,blk,0,st>>>(A,B,bias,bias2,Cf,Cb,Cb2,M,N,K,ldc,rawq,resid); break;
    case 1: gemm64<1><<<g,blk,0,st>>>(A,B,bias,bias2,Cf,Cb,Cb2,M,N,K,ldc,rawq,resid); break;
    case 2: gemm64<2><<<g,blk,0,st>>>(A,B,bias,bias2,Cf,Cb,Cb2,M,N,K,ldc,rawq,resid); break;
    default:gemm64<4><<<g,blk,0,st>>>(A,B,bias,bias2,Cf,Cb,Cb2,M,N,K,ldc,rawq,resid); break;
  }
}

extern "C" void kernel_launch(void* const* d_in, const int* in_sizes, int n_in,
                              void* d_out, int out_size, void* d_ws, size_t ws_size,
                              hipStream_t stream)
{
  const float* tgt    = (const float*)d_in[0];
  const float* seg    = (const float*)d_in[1];
  const float* dur    = (const float*)d_in[2];
  const float* src    = (const float*)d_in[3];
  const int*   tlens  = (const int*)d_in[4];
  const int*   lstart = (const int*)d_in[5];
  const float* valid  = (const float*)d_in[6];
  const unsigned char* pmask = (const unsigned char*)d_in[7];
  const float* grid_w0 = (const float*)d_in[8];
  const float* grid_b0 = (const float*)d_in[9];
  const float* grid_w1 = (const float*)d_in[10];
  const float* grid_b1 = (const float*)d_in[11];
  const float* qs_w0 = (const float*)d_in[12];
  const float* qs_b0 = (const float*)d_in[13];
  const float* qs_w1 = (const float*)d_in[14];
  const float* qs_b1 = (const float*)d_in[15];
  const float* sa_in_w  = (const float*)d_in[16];
  const float* sa_in_b  = (const float*)d_in[17];
  const float* sa_out_w = (const float*)d_in[18];
  const float* sa_out_b = (const float*)d_in[19];
  const float* n1_g = (const float*)d_in[20];
  const float* n1_b = (const float*)d_in[21];
  const float* n2_g = (const float*)d_in[22];
  const float* n2_b = (const float*)d_in[23];
  const float* n3_g = (const float*)d_in[24];
  const float* n3_b = (const float*)d_in[25];
  const float* off_w = (const float*)d_in[26];
  const float* off_b = (const float*)d_in[27];
  const float* aw_w  = (const float*)d_in[28];
  const float* aw_b  = (const float*)d_in[29];
  const float* val_w = (const float*)d_in[30];
  const float* val_b = (const float*)d_in[31];
  const float* outp_w = (const float*)d_in[32];
  const float* outp_b = (const float*)d_in[33];
  const float* ffn_w1 = (const float*)d_in[34];
  const float* ffn_b1 = (const float*)d_in[35];
  const float* ffn_w2 = (const float*)d_in[36];
  const float* ffn_b2 = (const float*)d_in[37];

  // bf16 weight region offsets (shorts); src bf16 follows weights
  const long W_G0=0, W_G1=131072, W_QS0=196608, W_QS1=262144, W_SAIN=327680,
             W_SAOUT=1507328, W_OFFAW=1900544, W_VAL=2195456,
             W_OUTP=2588672, W_FFN1=2981888, W_FFN2=4554752, W_SRC=6127616;

  char* ws = (char*)d_ws;
  short* wbf    = (short*)(ws + 0);
  short* srcbf  = wbf + W_SRC;
  short* sinebf = (short*)(ws + 70975488);
  short* ghbf   = (short*)(ws + 75890688);
  float* rawq   = (float*)(ws + 78348288);
  float* out    = (float*)(ws + 83263488);
  short* qbf    = (short*)(ws + 88178688);
  short* outbf  = qbf + (long)MROW*DM;
  short* t1bf   = (short*)(ws + 93093888);
  float* qpos   = (float*)(ws + 95551488);
  short* qkbf   = (short*)(ws + 100466688);   // [4800][512]
  short* vbf    = (short*)(ws + 105381888);   // [4800][256]
  short* attnbf = (short*)(ws + 107839488);
  float* tmpf   = (float*)(ws + 110297088);
  short* caqb   = (short*)(ws + 115212288);
  float* offaw  = (float*)(ws + 117669888);   // [4800][192]
  short* cabf   = (short*)(ws + 128729088);
  short* ffnhbf = (short*)(ws + 131186688);
  float* refin  = (float*)(ws + 141017088);
  unsigned char* val8 = (unsigned char*)(ws + 141132288);  // 6 x 29,360,128 -> ends 317,293,056

  CvtPtrs cp;
  cp.p[0]=grid_w0; cp.p[1]=grid_w1; cp.p[2]=qs_w0; cp.p[3]=qs_w1; cp.p[4]=sa_in_w;
  cp.p[5]=sa_out_w; cp.p[6]=off_w; cp.p[7]=aw_w; cp.p[8]=val_w; cp.p[9]=outp_w;
  cp.p[10]=ffn_w1; cp.p[11]=ffn_w2; cp.p[12]=src;
  cvt_all_kernel<<<dim3(34656), dim3(256), 0, stream>>>(cp, wbf);

  ew0_kernel<<<dim3(1200), dim3(256), 0, stream>>>(tgt, out, outbf);
  init_ref_kernel<<<dim3(MROW), dim3(256), 0, stream>>>(seg, dur, valid, sinebf, refin);

  // all 6 val projections upfront (src stays L3-resident across them)
  for (int l = 0; l < NLAY; ++l) {
    val_gemm<<<dim3(448, 2), dim3(512), 0, stream>>>(
        srcbf, wbf + W_VAL + (long)l*65536, val_b + l*256,
        val8 + (long)l*VAL8_STRIDE, pmask);
  }

  g64(stream, 1, sinebf, wbf + W_G0, grid_b0, nullptr, nullptr, ghbf, nullptr, MROW, 256, 512, 256);
  g64(stream, 0, ghbf,   wbf + W_G1, grid_b1, nullptr, rawq, nullptr, nullptr, MROW, 256, 256, 256);

  for (int l = 0; l < NLAY; ++l) {
    g64(stream, 1, outbf, wbf + W_QS0, qs_b0, nullptr, nullptr, t1bf, nullptr, MROW, 256, 256, 256);
    g64(stream, 2, t1bf,  wbf + W_QS1, qs_b1, nullptr, qpos, qbf, nullptr, MROW, 256, 256, 256,
        rawq, out);
    // self-attn projections split: qk from qbf (N=512), v from outbf (N=256)
    g64(stream, 0, qbf, wbf + W_SAIN + (long)l*196608, sa_in_b + l*768, nullptr,
        nullptr, qkbf, nullptr, MROW, 512, 256, 512);
    g64(stream, 0, outbf, wbf + W_SAIN + (long)l*196608 + 131072, sa_in_b + l*768 + 512, nullptr,
        nullptr, vbf, nullptr, MROW, 256, 256, 256);
    attn_mfma<<<dim3(256), dim3(256), 0, stream>>>(qkbf, vbf, attnbf);
    g64(stream, 0, attnbf, wbf + W_SAOUT + (long)l*65536, sa_out_b + l*256, nullptr,
        tmpf, nullptr, nullptr, MROW, 256, 256, 256);
    ln_kernel<<<dim3(MROW), dim3(256), 0, stream>>>(out, tmpf, n1_g + l*256, n1_b + l*256,
                                                    out, outbf, qpos, caqb);
    g64(stream, 4, caqb, wbf + W_OFFAW + (long)l*49152, off_b + l*96, aw_b + l*96,
        offaw, nullptr, nullptr, MROW, 192, 256, 192);
    sample_kernel<<<dim3(MROW), dim3(256), 0, stream>>>(
        val8 + (long)l*VAL8_STRIDE, offaw, refin, tlens, lstart, cabf);
    g64(stream, 0, cabf, wbf + W_OUTP + (long)l*65536, outp_b + l*256, nullptr,
        tmpf, nullptr, nullptr, MROW, 256, 256, 256);
    ln_kernel<<<dim3(MROW), dim3(256), 0, stream>>>(out, tmpf, n2_g + l*256, n2_b + l*256,
                                                    out, outbf, nullptr, nullptr);
    g64(stream, 1, outbf, wbf + W_FFN1 + (long)l*262144, ffn_b1 + l*1024, nullptr,
        nullptr, ffnhbf, nullptr, MROW, 1024, 256, 1024);
    g64(stream, 0, ffnhbf, wbf + W_FFN2 + (long)l*262144, ffn_b2 + l*256, nullptr,
        tmpf, nullptr, nullptr, MROW, 256, 1024, 256);
    float* of = (l == NLAY-1) ? (float*)d_out : out;
    ln_kernel<<<dim3(MROW), dim3(256), 0, stream>>>(out, tmpf, n3_g + l*256, n3_b + l*256,
                                                    of, outbf, nullptr, nullptr);
  }
}

// Round 15
// 1106.604 us; speedup vs baseline: 1.0936x; 1.0936x over previous
//
#include <hip/hip_runtime.h>
#include <cstdint>

#define NB   16
#define LQN  300
#define DM   256
#define NH   8
#define DH   32
#define NLV  3
#define DFFN 1024
#define NLAY 6
#define TT   7168
#define MROW (NB*LQN)   // 4800
#define SROW (NB*TT)    // 114688

typedef __attribute__((ext_vector_type(8))) short bf16x8;
typedef __attribute__((ext_vector_type(4))) float f32x4;

__device__ __forceinline__ float bf2f(short u) {
  unsigned x = ((unsigned)(unsigned short)u) << 16;
  return __builtin_bit_cast(float, x);
}
__device__ __forceinline__ short f2bf(float f) {
  unsigned u = __builtin_bit_cast(unsigned, f);
  u += 0x7fffu + ((u >> 16) & 1u);   // RNE
  return (short)(u >> 16);
}
// ---- manual fp8 e4m3fn encode/decode (R14-validated: absmax unchanged) ----
__device__ __forceinline__ unsigned f2fp8(float f) {
  const unsigned sgn = (__builtin_bit_cast(unsigned, f) >> 31) << 7;
  float a = fminf(fabsf(f), 448.0f);
  unsigned x = __builtin_bit_cast(unsigned, a);
  const int ex = (int)(x >> 23) - 127;
  unsigned enc;
  if (ex >= -6) {
    x += 0x7FFFFu + ((x >> 20) & 1u);          // RNE into 3-bit mantissa
    enc = (((x >> 23) - 120u) << 3) | ((x >> 20) & 7u);
  } else {
    enc = (unsigned)(int)__builtin_rintf(a * 512.0f);   // subnormal
  }
  return sgn | enc;
}
__device__ __forceinline__ float fp82f(unsigned v) {
  const unsigned e = (v >> 3) & 15u, m = v & 7u;
  float r;
  if (e == 0) r = (float)m * 0.001953125f;     // m * 2^-9
  else r = __builtin_bit_cast(float, ((e + 120u) << 23) | (m << 20));
  return (v & 0x80u) ? -r : r;
}
__device__ __forceinline__ void load_lds16(const void* g, void* l) {
  __builtin_amdgcn_global_load_lds(
      (const __attribute__((address_space(1))) unsigned int*)g,
      (__attribute__((address_space(3))) unsigned int*)l, 16, 0, 0);
}
#define MFMA(a,b,c) __builtin_amdgcn_mfma_f32_16x16x32_bf16((a),(b),(c),0,0,0)

// ---------------- weight + src fp32->bf16 conversion ----------------
struct CvtPtrs { const float* p[13]; };

__global__ __launch_bounds__(256)
void cvt_all_kernel(CvtPtrs ptrs, short* __restrict__ dst)
{
  const long gid = (long)blockIdx.x*256 + threadIdx.x;  // float4 units
  const long cums[14] = {0,32768,49152,65536,81920,376832,475136,512000,
                         548864,647168,745472,1138688,1531904,8871936};
  int s = 0;
  #pragma unroll
  for (int i = 1; i < 13; ++i) s += (gid >= cums[i]) ? 1 : 0;
  const long rel = gid - cums[s];
  const float4 v = ((const float4*)ptrs.p[s])[rel];
  long dstIdx = gid;
  if (s == 6) { const long l = rel/6144, w = rel%6144; dstIdx = 475136 + l*12288 + w; }
  else if (s == 7) { const long l = rel/6144, w = rel%6144; dstIdx = 475136 + l*12288 + 6144 + w; }
  ((short4*)dst)[dstIdx] = make_short4(f2bf(v.x), f2bf(v.y), f2bf(v.z), f2bf(v.w));
}

#define VLS 264   // padded LDS row stride (shorts)

// ---------------- val projection: BC=128 streaming GEMM -> fp8 output (in-loop) ----------------
__global__ __launch_bounds__(512, 2)
void val_gemm(const short* __restrict__ srcbf, const short* __restrict__ Bw,
              const float* __restrict__ bias, unsigned char* __restrict__ C8,
              const unsigned char* __restrict__ rowmask)
{
  __shared__ short Bs[128*VLS];   // 67,584 B
  const int tid = threadIdx.x, wid = tid >> 6, lane = tid & 63;
  const int fr = lane & 15, fq = lane >> 4;
  const int coff = blockIdx.y * 128;

  for (int t = tid; t < 4096; t += 512) {
    const int row = t >> 5, ch = t & 31;
    const int chs = ch ^ ((row >> 4) & 7);
    *(bf16x8*)&Bs[row*VLS + chs*8] = *(const bf16x8*)(Bw + (long)(coff + row)*256 + ch*8);
  }
  __syncthreads();

  float bv[8];
  #pragma unroll
  for (int j = 0; j < 2; ++j)
    *(float4*)&bv[j*4] = *(const float4*)(bias + coff + fr*8 + j*4);

  const int rbase = (blockIdx.x*8 + wid) * 32;   // 448*8 = 3584 = SROW/32

  bf16x8 ac0, ac1, an0, an1;
  ac0 = *(const bf16x8*)(srcbf + (long)(rbase + fr)*256 + fq*8);
  ac1 = *(const bf16x8*)(srcbf + (long)(rbase + 16 + fr)*256 + fq*8);

  f32x4 acc[2][8] = {};
  #pragma unroll
  for (int ks = 0; ks < 8; ++ks) {
    if (ks < 7) {
      an0 = *(const bf16x8*)(srcbf + (long)(rbase + fr)*256 + (ks+1)*32 + fq*8);
      an1 = *(const bf16x8*)(srcbf + (long)(rbase + 16 + fr)*256 + (ks+1)*32 + fq*8);
    }
    #pragma unroll
    for (int nt = 0; nt < 8; ++nt) {
      const int row = fr*8 + nt;
      const bf16x8 b = *(const bf16x8*)&Bs[row*VLS + (((ks*4 + fq) ^ ((row >> 4) & 7)))*8];
      acc[0][nt] = MFMA(ac0, b, acc[0][nt]);
      acc[1][nt] = MFMA(ac1, b, acc[1][nt]);
    }
    if (ks < 7) { ac0 = an0; ac1 = an1; }
  }

  #pragma unroll
  for (int h = 0; h < 2; ++h) {
    #pragma unroll
    for (int r = 0; r < 4; ++r) {
      const int grow = rbase + h*16 + fq*4 + r;
      const float msc = rowmask[grow] ? 0.0f : 1.0f;
      unsigned w0 = 0, w1 = 0;
      #pragma unroll
      for (int j = 0; j < 4; ++j) {
        w0 |= f2fp8((acc[h][j][r]   + bv[j])   * msc) << (j*8);
        w1 |= f2fp8((acc[h][4+j][r] + bv[4+j]) * msc) << (j*8);
      }
      uint2 o; o.x = w0; o.y = w1;
      *(uint2*)(C8 + (long)grow*256 + coff + fr*8) = o;
    }
  }
}

// ---------------- GEMM 64x64 tile, A[M,K] @ B[N,K]^T + bias (R3-proven) ----------------
// EPI: 0 plain, 1 relu->Cb, 2 qpos, 4 two-bias->Cf
template<int EPI>
__global__ __launch_bounds__(256)
void gemm64(const short* __restrict__ A, const short* __restrict__ B,
            const float* __restrict__ bias, const float* __restrict__ bias2,
            float* __restrict__ Cf, short* __restrict__ Cb, short* __restrict__ Cb2,
            int M, int N, int K, int ldc,
            const float* __restrict__ rawq, const float* __restrict__ resid)
{
  __shared__ short As[2][64*64];
  __shared__ short Bs[2][64*64];
  const int tid = threadIdx.x, wid = tid >> 6, lane = tid & 63;
  const int wr = wid >> 1, wc = wid & 1;
  const int fr = lane & 15, fq = lane >> 4;
  const int bm = blockIdx.x, bn = blockIdx.y;
  const int lrow = lane >> 3;
  const int schk = ((lane & 7) ^ lrow) * 8;
  const int nk = K >> 6;

  f32x4 acc[2][2] = {};

  auto stg = [&](int kt, int bsel) {
    const int k0 = kt << 6;
    #pragma unroll
    for (int i = 0; i < 2; ++i) {
      const int rr = wid*16 + i*8 + lrow;
      load_lds16(A + (long)(bm*64 + rr)*K + k0 + schk, &As[bsel][(wid*16 + i*8)*64]);
      load_lds16(B + (long)(bn*64 + rr)*K + k0 + schk, &Bs[bsel][(wid*16 + i*8)*64]);
    }
  };

  stg(0, 0);
  for (int t = 0; t < nk; ++t) {
    const int cur = t & 1;
    if (t + 1 < nk) {
      stg(t + 1, cur ^ 1);
      asm volatile("s_waitcnt vmcnt(4)" ::: "memory");
    } else {
      asm volatile("s_waitcnt vmcnt(0)" ::: "memory");
    }
    __builtin_amdgcn_s_barrier();
    __builtin_amdgcn_sched_barrier(0);
    #pragma unroll
    for (int kk = 0; kk < 64; kk += 32) {
      bf16x8 af[2], bv[2];
      #pragma unroll
      for (int mi = 0; mi < 2; ++mi)
        af[mi] = *(const bf16x8*)&As[cur][(wr*32 + mi*16 + fr)*64 + (((kk>>3)+fq) ^ (fr&7))*8];
      #pragma unroll
      for (int ni = 0; ni < 2; ++ni)
        bv[ni] = *(const bf16x8*)&Bs[cur][(wc*32 + ni*16 + fr)*64 + (((kk>>3)+fq) ^ (fr&7))*8];
      #pragma unroll
      for (int mi = 0; mi < 2; ++mi)
        #pragma unroll
        for (int ni = 0; ni < 2; ++ni)
          acc[mi][ni] = MFMA(af[mi], bv[ni], acc[mi][ni]);
    }
    __builtin_amdgcn_s_barrier();
  }

  #pragma unroll
  for (int mi = 0; mi < 2; ++mi) {
    #pragma unroll
    for (int r = 0; r < 4; ++r) {
      const int grow = bm*64 + wr*32 + mi*16 + fq*4 + r;
      #pragma unroll
      for (int ni = 0; ni < 2; ++ni) {
        const int gcol = bn*64 + wc*32 + ni*16 + fr;
        float v = acc[mi][ni][r];
        if (EPI == 4) v += (gcol < 96) ? bias[gcol] : bias2[gcol-96];
        else v += bias[gcol];
        const long off = (long)grow*ldc + gcol;
        if (EPI == 0) {
          if (Cf) Cf[off] = v;
          if (Cb) Cb[off] = f2bf(v);
        } else if (EPI == 1) {
          Cb[off] = f2bf(fmaxf(v, 0.0f));
        } else if (EPI == 2) {
          const float qp = v * rawq[off];
          Cf[off] = qp;
          Cb[off] = f2bf(resid[off] + qp);
        } else if (EPI == 4) {
          Cf[off] = v;
        }
      }
    }
  }
}

// ---------------- out = tgt (f32 + bf16 copies) ----------------
__global__ __launch_bounds__(256)
void ew0_kernel(const float* __restrict__ tgt, float* __restrict__ out, short* __restrict__ outbf)
{
  const long i = (long)blockIdx.x*256 + threadIdx.x;
  const float4 v = ((const float4*)tgt)[i];
  ((float4*)out)[i] = v;
  ((short4*)outbf)[i] = make_short4(f2bf(v.x), f2bf(v.y), f2bf(v.z), f2bf(v.w));
}

// ---------------- ref / ref_in / sine embedding ----------------
__global__ __launch_bounds__(256)
void init_ref_kernel(const float* __restrict__ seg, const float* __restrict__ dur,
                     const float* __restrict__ valid,
                     short* __restrict__ sinebf, float* __restrict__ refin)
{
  const int m = blockIdx.x;
  const int n = m / LQN;
  const int t = threadIdx.x;
  const float c = seg[(long)m*2 + 0];
  const float w = __expf(seg[(long)m*2 + 1]);
  const float e = (float)(t & ~1) * (1.0f/256.0f);
  const float invdim = __expf(-e * 9.2103403719761836f);
  const float twopi = 6.2831853071795864f;
  const float a0 = c * twopi * invdim;
  const float a1 = w * twopi * invdim;
  const float v0 = (t & 1) ? cosf(a0) : sinf(a0);
  const float v1 = (t & 1) ? cosf(a1) : sinf(a1);
  sinebf[(long)m*512 + t]       = f2bf(v0);
  sinebf[(long)m*512 + 256 + t] = f2bf(v1);
  if (t < 6) {
    const int l = t >> 1, cc = t & 1;
    const float rv = cc ? w : c;
    refin[(long)m*6 + l*2 + cc] = rv / dur[n] * valid[n*NLV + l];
  }
}

// ---------------- MFMA attention ----------------
#define KPAD 320
#define KSTR 40
#define VSTR 328
#define PSTR 328

__global__ __launch_bounds__(256)
void attn_mfma(const short* __restrict__ qk, const short* __restrict__ vv,
               short* __restrict__ outb)
{
  __shared__ short Kl[KPAD*KSTR];
  __shared__ short Vt[DH*VSTR];
  __shared__ short Pl[4][16*PSTR];
  const int b = blockIdx.x;
  const int half = b & 1, h = (b >> 1) & 7, n = b >> 4;
  const int tid = threadIdx.x, wid = tid >> 6, lane = tid & 63;
  const int fr = lane & 15, fq = lane >> 4;

  const short* qkn = qk + (long)n*LQN*512;
  const short* vn  = vv + (long)n*LQN*256;

  for (int t = tid; t < KPAD*4; t += 256) {
    const int r = t >> 2, c = t & 3;
    bf16x8 kv = {}, vw = {};
    if (r < LQN) {
      kv = *(const bf16x8*)(qkn + (long)r*512 + 256 + h*32 + c*8);
      vw = *(const bf16x8*)(vn  + (long)r*256 + h*32 + c*8);
    }
    *(bf16x8*)&Kl[r*KSTR + c*8] = kv;
    #pragma unroll
    for (int j = 0; j < 8; ++j) Vt[(c*8+j)*VSTR + r] = vw[j];
  }
  for (int t = tid; t < 4*16*24; t += 256) {
    const int w = t / (16*24), rr = (t / 24) & 15, cc = t % 24;
    Pl[w][rr*PSTR + 304 + cc] = 0;
  }
  __syncthreads();

  const int tlo = half ? 10 : 0, thi = half ? 19 : 10;
  const float scl2 = 0.17677669529663687f * 1.4426950408889634f;

  for (int qt = tlo + wid; qt < thi; qt += 4) {
    const int q0 = qt * 16;
    const int qrow = min(q0 + fr, LQN-1);
    const bf16x8 qf = *(const bf16x8*)(qkn + (long)qrow*512 + h*32 + fq*8);
    f32x4 s[19];
    #pragma unroll
    for (int t = 0; t < 19; ++t) {
      const bf16x8 kf = *(const bf16x8*)&Kl[(t*16+fr)*KSTR + fq*8];
      s[t] = MFMA(qf, kf, ((f32x4){0.f,0.f,0.f,0.f}));
    }
    float mx[4] = {-3e38f,-3e38f,-3e38f,-3e38f};
    #pragma unroll
    for (int t = 0; t < 19; ++t) {
      const bool valid = (t < 18) || (fr < 12);
      #pragma unroll
      for (int r = 0; r < 4; ++r) if (valid) mx[r] = fmaxf(mx[r], s[t][r]);
    }
    #pragma unroll
    for (int r = 0; r < 4; ++r) {
      #pragma unroll
      for (int o = 1; o < 16; o <<= 1) mx[r] = fmaxf(mx[r], __shfl_xor(mx[r], o));
      mx[r] *= scl2;
    }
    float l[4] = {0.f,0.f,0.f,0.f};
    #pragma unroll
    for (int t = 0; t < 19; ++t) {
      const bool valid = (t < 18) || (fr < 12);
      #pragma unroll
      for (int r = 0; r < 4; ++r) {
        const float p = valid ? exp2f(s[t][r]*scl2 - mx[r]) : 0.0f;
        l[r] += p;
        Pl[wid][(fq*4+r)*PSTR + t*16 + fr] = f2bf(p);
      }
    }
    #pragma unroll
    for (int r = 0; r < 4; ++r) {
      #pragma unroll
      for (int o = 1; o < 16; o <<= 1) l[r] += __shfl_xor(l[r], o);
    }
    f32x4 o0 = {}, o1 = {};
    #pragma unroll
    for (int ck = 0; ck < 10; ++ck) {
      const bf16x8 pf = *(const bf16x8*)&Pl[wid][fr*PSTR + ck*32 + fq*8];
      const bf16x8 v0 = *(const bf16x8*)&Vt[fr*VSTR + ck*32 + fq*8];
      const bf16x8 v1 = *(const bf16x8*)&Vt[(16+fr)*VSTR + ck*32 + fq*8];
      o0 = MFMA(pf, v0, o0);
      o1 = MFMA(pf, v1, o1);
    }
    #pragma unroll
    for (int r = 0; r < 4; ++r) {
      const int qq = q0 + fq*4 + r;
      if (qq < LQN) {
        const float inv = 1.0f / l[r];
        outb[((long)(n*LQN+qq))*256 + h*32 + fr]      = f2bf(o0[r]*inv);
        outb[((long)(n*LQN+qq))*256 + h*32 + 16 + fr] = f2bf(o1[r]*inv);
      }
    }
  }
}

// ---------------- residual + LayerNorm (+ optional caq = y+qpos) ----------------
__global__ __launch_bounds__(256)
void ln_kernel(const float* __restrict__ resid, const float* __restrict__ delta,
               const float* __restrict__ g, const float* __restrict__ b,
               float* __restrict__ of, short* __restrict__ ob,
               const float* __restrict__ qpos, short* __restrict__ caqb)
{
  const int m = blockIdx.x, c = threadIdx.x;
  const long idx = (long)m*DM + c;
  const float x = resid[idx] + delta[idx];
  float s = x, s2 = x*x;
  #pragma unroll
  for (int o = 1; o < 64; o <<= 1) { s += __shfl_xor(s, o); s2 += __shfl_xor(s2, o); }
  __shared__ float rs[4], rs2[4];
  const int w = c >> 6;
  if ((c & 63) == 0) { rs[w] = s; rs2[w] = s2; }
  __syncthreads();
  s  = rs[0]+rs[1]+rs[2]+rs[3];
  s2 = rs2[0]+rs2[1]+rs2[2]+rs2[3];
  const float mean = s * (1.0f/DM);
  const float var  = s2 * (1.0f/DM) - mean*mean;
  const float y = (x - mean) * rsqrtf(var + 1e-5f) * g[c] + b[c];
  of[idx] = y;
  if (ob) ob[idx] = f2bf(y);
  if (qpos) caqb[idx] = f2bf(y + qpos[idx]);
}

// ---------------- sampling: fused prep (softmax+bilinear) + gather-MAC, fp8 val ----------------
__global__ __launch_bounds__(256)
void sample_kernel(const unsigned char* __restrict__ val8,
                   const float* __restrict__ offaw, const float* __restrict__ refin,
                   const int* __restrict__ tlens, const int* __restrict__ lstart,
                   short* __restrict__ cab)
{
  const int m = blockIdx.x;
  const int n = m / LQN;
  const int tid = threadIdx.x;
  __shared__ int2  lI[96];
  __shared__ float2 lW[96];
  if ((tid & 31) == 0) {
    const int h = tid >> 5;
    const float* row = offaw + (long)m*192;
    float aw[12];
    float mx = -1e30f;
    #pragma unroll
    for (int lp = 0; lp < 12; ++lp) { aw[lp] = row[96 + h*12 + lp]; mx = fmaxf(mx, aw[lp]); }
    float sum = 0.0f;
    #pragma unroll
    for (int lp = 0; lp < 12; ++lp) { aw[lp] = __expf(aw[lp]-mx); sum += aw[lp]; }
    const float invs = 1.0f / sum;
    #pragma unroll
    for (int lp = 0; lp < 12; ++lp) {
      const int l = lp >> 2;
      const int tli = tlens[l];
      const float off = row[h*12 + lp];
      const float loc = refin[(long)m*6 + l*2] + off * 0.25f * refin[(long)m*6 + l*2 + 1] * 0.5f;
      const float x = loc * (float)tli - 0.5f;
      const float x0f = floorf(x);
      const float f = x - x0f;
      const int x0 = (int)x0f;
      const int i0 = lstart[l] + min(max(x0,   0), tli-1);
      const int i1 = lstart[l] + min(max(x0+1, 0), tli-1);
      const float wgt = aw[lp]*invs;
      const float w0 = (x0   >= 0 && x0   < tli) ? wgt*(1.0f-f) : 0.0f;
      const float w1 = (x0+1 >= 0 && x0+1 < tli) ? wgt*f        : 0.0f;
      lI[h*12 + lp] = make_int2(i0, i1);
      lW[h*12 + lp] = make_float2(w0, w1);
    }
  }
  __syncthreads();
  const int h = tid >> 5;
  const unsigned char* vb = val8 + (long)n*TT*256;
  float acc = 0.0f;
  #pragma unroll
  for (int lp = 0; lp < 12; ++lp) {
    const int e = h*12 + lp;
    const int2 ii = lI[e];
    const float2 ww = lW[e];
    acc += ww.x * fp82f(vb[(long)ii.x*256 + tid]) + ww.y * fp82f(vb[(long)ii.y*256 + tid]);
  }
  cab[(long)m*DM + tid] = f2bf(acc);
}

// ---------------- host side ----------------
static inline void g64(hipStream_t st, int epi, const short* A, const short* B,
                       const float* bias, const float* bias2,
                       float* Cf, short* Cb, short* Cb2,
                       int M, int N, int K, int ldc,
                       const float* rawq = nullptr, const float* resid = nullptr)
{
  dim3 g(M/64, N/64), blk(256);
  switch (epi) {
    case 0: gemm64<0><<<g,blk,0,st>>>(A,B,bias,bias2,Cf,Cb,Cb2,M,N,K,ldc,rawq,resid); break;
    case 1: gemm64<1><<<g,blk,0,st>>>(A,B,bias,bias2,Cf,Cb,Cb2,M,N,K,ldc,rawq,resid); break;
    case 2: gemm64<2><<<g,blk,0,st>>>(A,B,bias,bias2,Cf,Cb,Cb2,M,N,K,ldc,rawq,resid); break;
    default:gemm64<4><<<g,blk,0,st>>>(A,B,bias,bias2,Cf,Cb,Cb2,M,N,K,ldc,rawq,resid); break;
  }
}

extern "C" void kernel_launch(void* const* d_in, const int* in_sizes, int n_in,
                              void* d_out, int out_size, void* d_ws, size_t ws_size,
                              hipStream_t stream)
{
  const float* tgt    = (const float*)d_in[0];
  const float* seg    = (const float*)d_in[1];
  const float* dur    = (const float*)d_in[2];
  const float* src    = (const float*)d_in[3];
  const int*   tlens  = (const int*)d_in[4];
  const int*   lstart = (const int*)d_in[5];
  const float* valid  = (const float*)d_in[6];
  const unsigned char* pmask = (const unsigned char*)d_in[7];
  const float* grid_w0 = (const float*)d_in[8];
  const float* grid_b0 = (const float*)d_in[9];
  const float* grid_w1 = (const float*)d_in[10];
  const float* grid_b1 = (const float*)d_in[11];
  const float* qs_w0 = (const float*)d_in[12];
  const float* qs_b0 = (const float*)d_in[13];
  const float* qs_w1 = (const float*)d_in[14];
  const float* qs_b1 = (const float*)d_in[15];
  const float* sa_in_w  = (const float*)d_in[16];
  const float* sa_in_b  = (const float*)d_in[17];
  const float* sa_out_w = (const float*)d_in[18];
  const float* sa_out_b = (const float*)d_in[19];
  const float* n1_g = (const float*)d_in[20];
  const float* n1_b = (const float*)d_in[21];
  const float* n2_g = (const float*)d_in[22];
  const float* n2_b = (const float*)d_in[23];
  const float* n3_g = (const float*)d_in[24];
  const float* n3_b = (const float*)d_in[25];
  const float* off_w = (const float*)d_in[26];
  const float* off_b = (const float*)d_in[27];
  const float* aw_w  = (const float*)d_in[28];
  const float* aw_b  = (const float*)d_in[29];
  const float* val_w = (const float*)d_in[30];
  const float* val_b = (const float*)d_in[31];
  const float* outp_w = (const float*)d_in[32];
  const float* outp_b = (const float*)d_in[33];
  const float* ffn_w1 = (const float*)d_in[34];
  const float* ffn_b1 = (const float*)d_in[35];
  const float* ffn_w2 = (const float*)d_in[36];
  const float* ffn_b2 = (const float*)d_in[37];

  // bf16 weight region offsets (shorts); src bf16 follows weights
  const long W_G0=0, W_G1=131072, W_QS0=196608, W_QS1=262144, W_SAIN=327680,
             W_SAOUT=1507328, W_OFFAW=1900544, W_VAL=2195456,
             W_OUTP=2588672, W_FFN1=2981888, W_FFN2=4554752, W_SRC=6127616;

  char* ws = (char*)d_ws;
  short* wbf    = (short*)(ws + 0);
  short* srcbf  = wbf + W_SRC;
  short* sinebf = (short*)(ws + 70975488);
  short* ghbf   = (short*)(ws + 75890688);
  float* rawq   = (float*)(ws + 78348288);
  float* out    = (float*)(ws + 83263488);
  short* qbf    = (short*)(ws + 88178688);
  short* outbf  = qbf + (long)MROW*DM;
  short* t1bf   = (short*)(ws + 93093888);
  float* qpos   = (float*)(ws + 95551488);
  short* qkbf   = (short*)(ws + 100466688);   // [4800][512]
  short* vbf    = (short*)(ws + 105381888);   // [4800][256]
  short* attnbf = (short*)(ws + 107839488);
  float* tmpf   = (float*)(ws + 110297088);
  short* caqb   = (short*)(ws + 115212288);
  float* offaw  = (float*)(ws + 117669888);   // [4800][192]
  short* cabf   = (short*)(ws + 128729088);
  short* ffnhbf = (short*)(ws + 131186688);
  float* refin  = (float*)(ws + 141017088);
  unsigned char* val8 = (unsigned char*)(ws + 141132288);  // [114688][256] fp8, 29.3 MB

  CvtPtrs cp;
  cp.p[0]=grid_w0; cp.p[1]=grid_w1; cp.p[2]=qs_w0; cp.p[3]=qs_w1; cp.p[4]=sa_in_w;
  cp.p[5]=sa_out_w; cp.p[6]=off_w; cp.p[7]=aw_w; cp.p[8]=val_w; cp.p[9]=outp_w;
  cp.p[10]=ffn_w1; cp.p[11]=ffn_w2; cp.p[12]=src;
  cvt_all_kernel<<<dim3(34656), dim3(256), 0, stream>>>(cp, wbf);

  ew0_kernel<<<dim3(1200), dim3(256), 0, stream>>>(tgt, out, outbf);
  init_ref_kernel<<<dim3(MROW), dim3(256), 0, stream>>>(seg, dur, valid, sinebf, refin);

  g64(stream, 1, sinebf, wbf + W_G0, grid_b0, nullptr, nullptr, ghbf, nullptr, MROW, 256, 512, 256);
  g64(stream, 0, ghbf,   wbf + W_G1, grid_b1, nullptr, rawq, nullptr, nullptr, MROW, 256, 256, 256);

  for (int l = 0; l < NLAY; ++l) {
    g64(stream, 1, outbf, wbf + W_QS0, qs_b0, nullptr, nullptr, t1bf, nullptr, MROW, 256, 256, 256);
    g64(stream, 2, t1bf,  wbf + W_QS1, qs_b1, nullptr, qpos, qbf, nullptr, MROW, 256, 256, 256,
        rawq, out);
    // self-attn projections split: qk from qbf (N=512), v from outbf (N=256)
    g64(stream, 0, qbf, wbf + W_SAIN + (long)l*196608, sa_in_b + l*768, nullptr,
        nullptr, qkbf, nullptr, MROW, 512, 256, 512);
    g64(stream, 0, outbf, wbf + W_SAIN + (long)l*196608 + 131072, sa_in_b + l*768 + 512, nullptr,
        nullptr, vbf, nullptr, MROW, 256, 256, 256);
    attn_mfma<<<dim3(256), dim3(256), 0, stream>>>(qkbf, vbf, attnbf);
    g64(stream, 0, attnbf, wbf + W_SAOUT + (long)l*65536, sa_out_b + l*256, nullptr,
        tmpf, nullptr, nullptr, MROW, 256, 256, 256);
    ln_kernel<<<dim3(MROW), dim3(256), 0, stream>>>(out, tmpf, n1_g + l*256, n1_b + l*256,
                                                    out, outbf, qpos, caqb);
    g64(stream, 4, caqb, wbf + W_OFFAW + (long)l*49152, off_b + l*96, aw_b + l*96,
        offaw, nullptr, nullptr, MROW, 192, 256, 192);
    val_gemm<<<dim3(448, 2), dim3(512), 0, stream>>>(
        srcbf, wbf + W_VAL + (long)l*65536, val_b + l*256, val8, pmask);
    sample_kernel<<<dim3(MROW), dim3(256), 0, stream>>>(
        val8, offaw, refin, tlens, lstart, cabf);
    g64(stream, 0, cabf, wbf + W_OUTP + (long)l*65536, outp_b + l*256, nullptr,
        tmpf, nullptr, nullptr, MROW, 256, 256, 256);
    ln_kernel<<<dim3(MROW), dim3(256), 0, stream>>>(out, tmpf, n2_g + l*256, n2_b + l*256,
                                                    out, outbf, nullptr, nullptr);
    g64(stream, 1, outbf, wbf + W_FFN1 + (long)l*262144, ffn_b1 + l*1024, nullptr,
        nullptr, ffnhbf, nullptr, MROW, 1024, 256, 1024);
    g64(stream, 0, ffnhbf, wbf + W_FFN2 + (long)l*262144, ffn_b2 + l*256, nullptr,
        tmpf, nullptr, nullptr, MROW, 256, 1024, 256);
    float* of = (l == NLAY-1) ? (float*)d_out : out;
    ln_kernel<<<dim3(MROW), dim3(256), 0, stream>>>(out, tmpf, n3_g + l*256, n3_b + l*256,
                                                    of, outbf, nullptr, nullptr);
  }
}

// Round 16
// 965.651 us; speedup vs baseline: 1.2532x; 1.1460x over previous
//
#include <hip/hip_runtime.h>
#include <cstdint>

#define NB   16
#define LQN  300
#define DM   256
#define NH   8
#define DH   32
#define NLV  3
#define DFFN 1024
#define NLAY 6
#define TT   7168
#define MROW (NB*LQN)   // 4800
#define SROW (NB*TT)    // 114688

typedef __attribute__((ext_vector_type(8))) short bf16x8;
typedef __attribute__((ext_vector_type(4))) float f32x4;

__device__ __forceinline__ float bf2f(short u) {
  unsigned x = ((unsigned)(unsigned short)u) << 16;
  return __builtin_bit_cast(float, x);
}
__device__ __forceinline__ short f2bf(float f) {
  unsigned u = __builtin_bit_cast(unsigned, f);
  u += 0x7fffu + ((u >> 16) & 1u);   // RNE
  return (short)(u >> 16);
}
__device__ __forceinline__ void load_lds16(const void* g, void* l) {
  __builtin_amdgcn_global_load_lds(
      (const __attribute__((address_space(1))) unsigned int*)g,
      (__attribute__((address_space(3))) unsigned int*)l, 16, 0, 0);
}
#define MFMA(a,b,c) __builtin_amdgcn_mfma_f32_16x16x32_bf16((a),(b),(c),0,0,0)

// ---------------- weight + src fp32->bf16 conversion ----------------
struct CvtPtrs { const float* p[13]; };

__global__ __launch_bounds__(256)
void cvt_all_kernel(CvtPtrs ptrs, short* __restrict__ dst)
{
  const long gid = (long)blockIdx.x*256 + threadIdx.x;  // float4 units
  const long cums[14] = {0,32768,49152,65536,81920,376832,475136,512000,
                         548864,647168,745472,1138688,1531904,8871936};
  int s = 0;
  #pragma unroll
  for (int i = 1; i < 13; ++i) s += (gid >= cums[i]) ? 1 : 0;
  const long rel = gid - cums[s];
  const float4 v = ((const float4*)ptrs.p[s])[rel];
  long dstIdx = gid;
  if (s == 6) { const long l = rel/6144, w = rel%6144; dstIdx = 475136 + l*12288 + w; }
  else if (s == 7) { const long l = rel/6144, w = rel%6144; dstIdx = 475136 + l*12288 + 6144 + w; }
  ((short4*)dst)[dstIdx] = make_short4(f2bf(v.x), f2bf(v.y), f2bf(v.z), f2bf(v.w));
}

#define VLS 264   // padded LDS row stride (shorts)

// ---------------- val projection: BC=128 streaming GEMM, 2 blocks/CU (R13-proven) ----------------
__global__ __launch_bounds__(512, 2)
void val_gemm(const short* __restrict__ srcbf, const short* __restrict__ Bw,
              const float* __restrict__ bias, short* __restrict__ Cb,
              const unsigned char* __restrict__ rowmask)
{
  __shared__ short Bs[128*VLS];   // 67,584 B
  const int tid = threadIdx.x, wid = tid >> 6, lane = tid & 63;
  const int fr = lane & 15, fq = lane >> 4;
  const int coff = blockIdx.y * 128;

  for (int t = tid; t < 4096; t += 512) {
    const int row = t >> 5, ch = t & 31;
    const int chs = ch ^ ((row >> 4) & 7);
    *(bf16x8*)&Bs[row*VLS + chs*8] = *(const bf16x8*)(Bw + (long)(coff + row)*256 + ch*8);
  }
  __syncthreads();

  float bv[8];
  #pragma unroll
  for (int j = 0; j < 2; ++j)
    *(float4*)&bv[j*4] = *(const float4*)(bias + coff + fr*8 + j*4);

  const int rbase = (blockIdx.x*8 + wid) * 32;   // 448*8 = 3584 = SROW/32

  bf16x8 ac0, ac1, an0, an1;
  ac0 = *(const bf16x8*)(srcbf + (long)(rbase + fr)*256 + fq*8);
  ac1 = *(const bf16x8*)(srcbf + (long)(rbase + 16 + fr)*256 + fq*8);

  f32x4 acc[2][8] = {};
  #pragma unroll
  for (int ks = 0; ks < 8; ++ks) {
    if (ks < 7) {
      an0 = *(const bf16x8*)(srcbf + (long)(rbase + fr)*256 + (ks+1)*32 + fq*8);
      an1 = *(const bf16x8*)(srcbf + (long)(rbase + 16 + fr)*256 + (ks+1)*32 + fq*8);
    }
    #pragma unroll
    for (int nt = 0; nt < 8; ++nt) {
      const int row = fr*8 + nt;
      const bf16x8 b = *(const bf16x8*)&Bs[row*VLS + (((ks*4 + fq) ^ ((row >> 4) & 7)))*8];
      acc[0][nt] = MFMA(ac0, b, acc[0][nt]);
      acc[1][nt] = MFMA(ac1, b, acc[1][nt]);
    }
    if (ks < 7) { ac0 = an0; ac1 = an1; }
  }

  #pragma unroll
  for (int h = 0; h < 2; ++h) {
    #pragma unroll
    for (int r = 0; r < 4; ++r) {
      const int grow = rbase + h*16 + fq*4 + r;
      const float msc = rowmask[grow] ? 0.0f : 1.0f;
      bf16x8 o;
      #pragma unroll
      for (int j = 0; j < 8; ++j) o[j] = f2bf((acc[h][j][r] + bv[j]) * msc);
      *(bf16x8*)(Cb + (long)grow*256 + coff + fr*8) = o;
    }
  }
}

// ---------------- GEMM 64x64 tile, A[M,K] @ B[N,K]^T + bias (R3-proven) ----------------
// EPI: 0 plain, 1 relu->Cb, 2 qpos, 4 two-bias->Cf
template<int EPI>
__global__ __launch_bounds__(256)
void gemm64(const short* __restrict__ A, const short* __restrict__ B,
            const float* __restrict__ bias, const float* __restrict__ bias2,
            float* __restrict__ Cf, short* __restrict__ Cb, short* __restrict__ Cb2,
            int M, int N, int K, int ldc,
            const float* __restrict__ rawq, const float* __restrict__ resid)
{
  __shared__ short As[2][64*64];
  __shared__ short Bs[2][64*64];
  const int tid = threadIdx.x, wid = tid >> 6, lane = tid & 63;
  const int wr = wid >> 1, wc = wid & 1;
  const int fr = lane & 15, fq = lane >> 4;
  const int bm = blockIdx.x, bn = blockIdx.y;
  const int lrow = lane >> 3;
  const int schk = ((lane & 7) ^ lrow) * 8;
  const int nk = K >> 6;

  f32x4 acc[2][2] = {};

  auto stg = [&](int kt, int bsel) {
    const int k0 = kt << 6;
    #pragma unroll
    for (int i = 0; i < 2; ++i) {
      const int rr = wid*16 + i*8 + lrow;
      load_lds16(A + (long)(bm*64 + rr)*K + k0 + schk, &As[bsel][(wid*16 + i*8)*64]);
      load_lds16(B + (long)(bn*64 + rr)*K + k0 + schk, &Bs[bsel][(wid*16 + i*8)*64]);
    }
  };

  stg(0, 0);
  for (int t = 0; t < nk; ++t) {
    const int cur = t & 1;
    if (t + 1 < nk) {
      stg(t + 1, cur ^ 1);
      asm volatile("s_waitcnt vmcnt(4)" ::: "memory");
    } else {
      asm volatile("s_waitcnt vmcnt(0)" ::: "memory");
    }
    __builtin_amdgcn_s_barrier();
    __builtin_amdgcn_sched_barrier(0);
    #pragma unroll
    for (int kk = 0; kk < 64; kk += 32) {
      bf16x8 af[2], bv[2];
      #pragma unroll
      for (int mi = 0; mi < 2; ++mi)
        af[mi] = *(const bf16x8*)&As[cur][(wr*32 + mi*16 + fr)*64 + (((kk>>3)+fq) ^ (fr&7))*8];
      #pragma unroll
      for (int ni = 0; ni < 2; ++ni)
        bv[ni] = *(const bf16x8*)&Bs[cur][(wc*32 + ni*16 + fr)*64 + (((kk>>3)+fq) ^ (fr&7))*8];
      #pragma unroll
      for (int mi = 0; mi < 2; ++mi)
        #pragma unroll
        for (int ni = 0; ni < 2; ++ni)
          acc[mi][ni] = MFMA(af[mi], bv[ni], acc[mi][ni]);
    }
    __builtin_amdgcn_s_barrier();
  }

  #pragma unroll
  for (int mi = 0; mi < 2; ++mi) {
    #pragma unroll
    for (int r = 0; r < 4; ++r) {
      const int grow = bm*64 + wr*32 + mi*16 + fq*4 + r;
      #pragma unroll
      for (int ni = 0; ni < 2; ++ni) {
        const int gcol = bn*64 + wc*32 + ni*16 + fr;
        float v = acc[mi][ni][r];
        if (EPI == 4) v += (gcol < 96) ? bias[gcol] : bias2[gcol-96];
        else v += bias[gcol];
        const long off = (long)grow*ldc + gcol;
        if (EPI == 0) {
          if (Cf) Cf[off] = v;
          if (Cb) Cb[off] = f2bf(v);
        } else if (EPI == 1) {
          Cb[off] = f2bf(fmaxf(v, 0.0f));
        } else if (EPI == 2) {
          const float qp = v * rawq[off];
          Cf[off] = qp;
          Cb[off] = f2bf(resid[off] + qp);
        } else if (EPI == 4) {
          Cf[off] = v;
        }
      }
    }
  }
}

// ---------------- out = tgt (f32 + bf16 copies) ----------------
__global__ __launch_bounds__(256)
void ew0_kernel(const float* __restrict__ tgt, float* __restrict__ out, short* __restrict__ outbf)
{
  const long i = (long)blockIdx.x*256 + threadIdx.x;
  const float4 v = ((const float4*)tgt)[i];
  ((float4*)out)[i] = v;
  ((short4*)outbf)[i] = make_short4(f2bf(v.x), f2bf(v.y), f2bf(v.z), f2bf(v.w));
}

// ---------------- ref / ref_in / sine embedding ----------------
__global__ __launch_bounds__(256)
void init_ref_kernel(const float* __restrict__ seg, const float* __restrict__ dur,
                     const float* __restrict__ valid,
                     short* __restrict__ sinebf, float* __restrict__ refin)
{
  const int m = blockIdx.x;
  const int n = m / LQN;
  const int t = threadIdx.x;
  const float c = seg[(long)m*2 + 0];
  const float w = __expf(seg[(long)m*2 + 1]);
  const float e = (float)(t & ~1) * (1.0f/256.0f);
  const float invdim = __expf(-e * 9.2103403719761836f);
  const float twopi = 6.2831853071795864f;
  const float a0 = c * twopi * invdim;
  const float a1 = w * twopi * invdim;
  const float v0 = (t & 1) ? cosf(a0) : sinf(a0);
  const float v1 = (t & 1) ? cosf(a1) : sinf(a1);
  sinebf[(long)m*512 + t]       = f2bf(v0);
  sinebf[(long)m*512 + 256 + t] = f2bf(v1);
  if (t < 6) {
    const int l = t >> 1, cc = t & 1;
    const float rv = cc ? w : c;
    refin[(long)m*6 + l*2 + cc] = rv / dur[n] * valid[n*NLV + l];
  }
}

// ---------------- MFMA attention ----------------
#define KPAD 320
#define KSTR 40
#define VSTR 328
#define PSTR 328

__global__ __launch_bounds__(256)
void attn_mfma(const short* __restrict__ qk, const short* __restrict__ vv,
               short* __restrict__ outb)
{
  __shared__ short Kl[KPAD*KSTR];
  __shared__ short Vt[DH*VSTR];
  __shared__ short Pl[4][16*PSTR];
  const int b = blockIdx.x;
  const int half = b & 1, h = (b >> 1) & 7, n = b >> 4;
  const int tid = threadIdx.x, wid = tid >> 6, lane = tid & 63;
  const int fr = lane & 15, fq = lane >> 4;

  const short* qkn = qk + (long)n*LQN*512;
  const short* vn  = vv + (long)n*LQN*256;

  for (int t = tid; t < KPAD*4; t += 256) {
    const int r = t >> 2, c = t & 3;
    bf16x8 kv = {}, vw = {};
    if (r < LQN) {
      kv = *(const bf16x8*)(qkn + (long)r*512 + 256 + h*32 + c*8);
      vw = *(const bf16x8*)(vn  + (long)r*256 + h*32 + c*8);
    }
    *(bf16x8*)&Kl[r*KSTR + c*8] = kv;
    #pragma unroll
    for (int j = 0; j < 8; ++j) Vt[(c*8+j)*VSTR + r] = vw[j];
  }
  for (int t = tid; t < 4*16*24; t += 256) {
    const int w = t / (16*24), rr = (t / 24) & 15, cc = t % 24;
    Pl[w][rr*PSTR + 304 + cc] = 0;
  }
  __syncthreads();

  const int tlo = half ? 10 : 0, thi = half ? 19 : 10;
  const float scl2 = 0.17677669529663687f * 1.4426950408889634f;

  for (int qt = tlo + wid; qt < thi; qt += 4) {
    const int q0 = qt * 16;
    const int qrow = min(q0 + fr, LQN-1);
    const bf16x8 qf = *(const bf16x8*)(qkn + (long)qrow*512 + h*32 + fq*8);
    f32x4 s[19];
    #pragma unroll
    for (int t = 0; t < 19; ++t) {
      const bf16x8 kf = *(const bf16x8*)&Kl[(t*16+fr)*KSTR + fq*8];
      s[t] = MFMA(qf, kf, ((f32x4){0.f,0.f,0.f,0.f}));
    }
    float mx[4] = {-3e38f,-3e38f,-3e38f,-3e38f};
    #pragma unroll
    for (int t = 0; t < 19; ++t) {
      const bool valid = (t < 18) || (fr < 12);
      #pragma unroll
      for (int r = 0; r < 4; ++r) if (valid) mx[r] = fmaxf(mx[r], s[t][r]);
    }
    #pragma unroll
    for (int r = 0; r < 4; ++r) {
      #pragma unroll
      for (int o = 1; o < 16; o <<= 1) mx[r] = fmaxf(mx[r], __shfl_xor(mx[r], o));
      mx[r] *= scl2;
    }
    float l[4] = {0.f,0.f,0.f,0.f};
    #pragma unroll
    for (int t = 0; t < 19; ++t) {
      const bool valid = (t < 18) || (fr < 12);
      #pragma unroll
      for (int r = 0; r < 4; ++r) {
        const float p = valid ? exp2f(s[t][r]*scl2 - mx[r]) : 0.0f;
        l[r] += p;
        Pl[wid][(fq*4+r)*PSTR + t*16 + fr] = f2bf(p);
      }
    }
    #pragma unroll
    for (int r = 0; r < 4; ++r) {
      #pragma unroll
      for (int o = 1; o < 16; o <<= 1) l[r] += __shfl_xor(l[r], o);
    }
    f32x4 o0 = {}, o1 = {};
    #pragma unroll
    for (int ck = 0; ck < 10; ++ck) {
      const bf16x8 pf = *(const bf16x8*)&Pl[wid][fr*PSTR + ck*32 + fq*8];
      const bf16x8 v0 = *(const bf16x8*)&Vt[fr*VSTR + ck*32 + fq*8];
      const bf16x8 v1 = *(const bf16x8*)&Vt[(16+fr)*VSTR + ck*32 + fq*8];
      o0 = MFMA(pf, v0, o0);
      o1 = MFMA(pf, v1, o1);
    }
    #pragma unroll
    for (int r = 0; r < 4; ++r) {
      const int qq = q0 + fq*4 + r;
      if (qq < LQN) {
        const float inv = 1.0f / l[r];
        outb[((long)(n*LQN+qq))*256 + h*32 + fr]      = f2bf(o0[r]*inv);
        outb[((long)(n*LQN+qq))*256 + h*32 + 16 + fr] = f2bf(o1[r]*inv);
      }
    }
  }
}

// ---------------- residual + LayerNorm (+ optional caq = y+qpos) ----------------
__global__ __launch_bounds__(256)
void ln_kernel(const float* __restrict__ resid, const float* __restrict__ delta,
               const float* __restrict__ g, const float* __restrict__ b,
               float* __restrict__ of, short* __restrict__ ob,
               const float* __restrict__ qpos, short* __restrict__ caqb)
{
  const int m = blockIdx.x, c = threadIdx.x;
  const long idx = (long)m*DM + c;
  const float x = resid[idx] + delta[idx];
  float s = x, s2 = x*x;
  #pragma unroll
  for (int o = 1; o < 64; o <<= 1) { s += __shfl_xor(s, o); s2 += __shfl_xor(s2, o); }
  __shared__ float rs[4], rs2[4];
  const int w = c >> 6;
  if ((c & 63) == 0) { rs[w] = s; rs2[w] = s2; }
  __syncthreads();
  s  = rs[0]+rs[1]+rs[2]+rs[3];
  s2 = rs2[0]+rs2[1]+rs2[2]+rs2[3];
  const float mean = s * (1.0f/DM);
  const float var  = s2 * (1.0f/DM) - mean*mean;
  const float y = (x - mean) * rsqrtf(var + 1e-5f) * g[c] + b[c];
  of[idx] = y;
  if (ob) ob[idx] = f2bf(y);
  if (qpos) caqb[idx] = f2bf(y + qpos[idx]);
}

// ---------------- sampling: fused prep (softmax+bilinear) + gather-MAC ----------------
__global__ __launch_bounds__(256)
void sample_kernel(const short* __restrict__ val, int ldv,
                   const float* __restrict__ offaw, const float* __restrict__ refin,
                   const int* __restrict__ tlens, const int* __restrict__ lstart,
                   short* __restrict__ cab)
{
  const int m = blockIdx.x;
  const int n = m / LQN;
  const int tid = threadIdx.x;
  __shared__ int2  lI[96];
  __shared__ float2 lW[96];
  if ((tid & 31) == 0) {
    const int h = tid >> 5;
    const float* row = offaw + (long)m*192;
    float aw[12];
    float mx = -1e30f;
    #pragma unroll
    for (int lp = 0; lp < 12; ++lp) { aw[lp] = row[96 + h*12 + lp]; mx = fmaxf(mx, aw[lp]); }
    float sum = 0.0f;
    #pragma unroll
    for (int lp = 0; lp < 12; ++lp) { aw[lp] = __expf(aw[lp]-mx); sum += aw[lp]; }
    const float invs = 1.0f / sum;
    #pragma unroll
    for (int lp = 0; lp < 12; ++lp) {
      const int l = lp >> 2;
      const int tli = tlens[l];
      const float off = row[h*12 + lp];
      const float loc = refin[(long)m*6 + l*2] + off * 0.25f * refin[(long)m*6 + l*2 + 1] * 0.5f;
      const float x = loc * (float)tli - 0.5f;
      const float x0f = floorf(x);
      const float f = x - x0f;
      const int x0 = (int)x0f;
      const int i0 = lstart[l] + min(max(x0,   0), tli-1);
      const int i1 = lstart[l] + min(max(x0+1, 0), tli-1);
      const float wgt = aw[lp]*invs;
      const float w0 = (x0   >= 0 && x0   < tli) ? wgt*(1.0f-f) : 0.0f;
      const float w1 = (x0+1 >= 0 && x0+1 < tli) ? wgt*f        : 0.0f;
      lI[h*12 + lp] = make_int2(i0, i1);
      lW[h*12 + lp] = make_float2(w0, w1);
    }
  }
  __syncthreads();
  const int h = tid >> 5;
  const short* vb = val + (long)n*TT*ldv;
  float acc = 0.0f;
  #pragma unroll
  for (int lp = 0; lp < 12; ++lp) {
    const int e = h*12 + lp;
    const int2 ii = lI[e];
    const float2 ww = lW[e];
    acc += ww.x * bf2f(vb[(long)ii.x*ldv + tid]) + ww.y * bf2f(vb[(long)ii.y*ldv + tid]);
  }
  cab[(long)m*DM + tid] = f2bf(acc);
}

// ---------------- host side ----------------
static inline void g64(hipStream_t st, int epi, const short* A, const short* B,
                       const float* bias, const float* bias2,
                       float* Cf, short* Cb, short* Cb2,
                       int M, int N, int K, int ldc,
                       const float* rawq = nullptr, const float* resid = nullptr)
{
  dim3 g(M/64, N/64), blk(256);
  switch (epi) {
    case 0: gemm64<0><<<g,blk,0,st>>>(A,B,bias,bias2,Cf,Cb,Cb2,M,N,K,ldc,rawq,resid); break;
    case 1: gemm64<1><<<g,blk,0,st>>>(A,B,bias,bias2,Cf,Cb,Cb2,M,N,K,ldc,rawq,resid); break;
    case 2: gemm64<2><<<g,blk,0,st>>>(A,B,bias,bias2,Cf,Cb,Cb2,M,N,K,ldc,rawq,resid); break;
    default:gemm64<4><<<g,blk,0,st>>>(A,B,bias,bias2,Cf,Cb,Cb2,M,N,K,ldc,rawq,resid); break;
  }
}

extern "C" void kernel_launch(void* const* d_in, const int* in_sizes, int n_in,
                              void* d_out, int out_size, void* d_ws, size_t ws_size,
                              hipStream_t stream)
{
  const float* tgt    = (const float*)d_in[0];
  const float* seg    = (const float*)d_in[1];
  const float* dur    = (const float*)d_in[2];
  const float* src    = (const float*)d_in[3];
  const int*   tlens  = (const int*)d_in[4];
  const int*   lstart = (const int*)d_in[5];
  const float* valid  = (const float*)d_in[6];
  const unsigned char* pmask = (const unsigned char*)d_in[7];
  const float* grid_w0 = (const float*)d_in[8];
  const float* grid_b0 = (const float*)d_in[9];
  const float* grid_w1 = (const float*)d_in[10];
  const float* grid_b1 = (const float*)d_in[11];
  const float* qs_w0 = (const float*)d_in[12];
  const float* qs_b0 = (const float*)d_in[13];
  const float* qs_w1 = (const float*)d_in[14];
  const float* qs_b1 = (const float*)d_in[15];
  const float* sa_in_w  = (const float*)d_in[16];
  const float* sa_in_b  = (const float*)d_in[17];
  const float* sa_out_w = (const float*)d_in[18];
  const float* sa_out_b = (const float*)d_in[19];
  const float* n1_g = (const float*)d_in[20];
  const float* n1_b = (const float*)d_in[21];
  const float* n2_g = (const float*)d_in[22];
  const float* n2_b = (const float*)d_in[23];
  const float* n3_g = (const float*)d_in[24];
  const float* n3_b = (const float*)d_in[25];
  const float* off_w = (const float*)d_in[26];
  const float* off_b = (const float*)d_in[27];
  const float* aw_w  = (const float*)d_in[28];
  const float* aw_b  = (const float*)d_in[29];
  const float* val_w = (const float*)d_in[30];
  const float* val_b = (const float*)d_in[31];
  const float* outp_w = (const float*)d_in[32];
  const float* outp_b = (const float*)d_in[33];
  const float* ffn_w1 = (const float*)d_in[34];
  const float* ffn_b1 = (const float*)d_in[35];
  const float* ffn_w2 = (const float*)d_in[36];
  const float* ffn_b2 = (const float*)d_in[37];

  // bf16 weight region offsets (shorts); src bf16 follows weights
  const long W_G0=0, W_G1=131072, W_QS0=196608, W_QS1=262144, W_SAIN=327680,
             W_SAOUT=1507328, W_OFFAW=1900544, W_VAL=2195456,
             W_OUTP=2588672, W_FFN1=2981888, W_FFN2=4554752, W_SRC=6127616;

  char* ws = (char*)d_ws;
  short* wbf    = (short*)(ws + 0);
  short* srcbf  = wbf + W_SRC;
  short* sinebf = (short*)(ws + 70975488);
  short* ghbf   = (short*)(ws + 75890688);
  float* rawq   = (float*)(ws + 78348288);
  float* out    = (float*)(ws + 83263488);
  short* qbf    = (short*)(ws + 88178688);
  short* outbf  = qbf + (long)MROW*DM;
  short* t1bf   = (short*)(ws + 93093888);
  float* qpos   = (float*)(ws + 95551488);
  short* qkbf   = (short*)(ws + 100466688);   // [4800][512]
  short* vbf    = (short*)(ws + 105381888);   // [4800][256]
  short* attnbf = (short*)(ws + 107839488);
  float* tmpf   = (float*)(ws + 110297088);
  short* caqb   = (short*)(ws + 115212288);
  float* offaw  = (float*)(ws + 117669888);   // [4800][192]
  short* cabf   = (short*)(ws + 128729088);
  short* ffnhbf = (short*)(ws + 131186688);
  float* refin  = (float*)(ws + 141017088);
  short* valbf  = (short*)(ws + 141132288);   // [114688][256]

  CvtPtrs cp;
  cp.p[0]=grid_w0; cp.p[1]=grid_w1; cp.p[2]=qs_w0; cp.p[3]=qs_w1; cp.p[4]=sa_in_w;
  cp.p[5]=sa_out_w; cp.p[6]=off_w; cp.p[7]=aw_w; cp.p[8]=val_w; cp.p[9]=outp_w;
  cp.p[10]=ffn_w1; cp.p[11]=ffn_w2; cp.p[12]=src;
  cvt_all_kernel<<<dim3(34656), dim3(256), 0, stream>>>(cp, wbf);

  ew0_kernel<<<dim3(1200), dim3(256), 0, stream>>>(tgt, out, outbf);
  init_ref_kernel<<<dim3(MROW), dim3(256), 0, stream>>>(seg, dur, valid, sinebf, refin);

  g64(stream, 1, sinebf, wbf + W_G0, grid_b0, nullptr, nullptr, ghbf, nullptr, MROW, 256, 512, 256);
  g64(stream, 0, ghbf,   wbf + W_G1, grid_b1, nullptr, rawq, nullptr, nullptr, MROW, 256, 256, 256);

  for (int l = 0; l < NLAY; ++l) {
    g64(stream, 1, outbf, wbf + W_QS0, qs_b0, nullptr, nullptr, t1bf, nullptr, MROW, 256, 256, 256);
    g64(stream, 2, t1bf,  wbf + W_QS1, qs_b1, nullptr, qpos, qbf, nullptr, MROW, 256, 256, 256,
        rawq, out);
    // self-attn projections split: qk from qbf (N=512), v from outbf (N=256)
    g64(stream, 0, qbf, wbf + W_SAIN + (long)l*196608, sa_in_b + l*768, nullptr,
        nullptr, qkbf, nullptr, MROW, 512, 256, 512);
    g64(stream, 0, outbf, wbf + W_SAIN + (long)l*196608 + 131072, sa_in_b + l*768 + 512, nullptr,
        nullptr, vbf, nullptr, MROW, 256, 256, 256);
    attn_mfma<<<dim3(256), dim3(256), 0, stream>>>(qkbf, vbf, attnbf);
    g64(stream, 0, attnbf, wbf + W_SAOUT + (long)l*65536, sa_out_b + l*256, nullptr,
        tmpf, nullptr, nullptr, MROW, 256, 256, 256);
    ln_kernel<<<dim3(MROW), dim3(256), 0, stream>>>(out, tmpf, n1_g + l*256, n1_b + l*256,
                                                    out, outbf, qpos, caqb);
    g64(stream, 4, caqb, wbf + W_OFFAW + (long)l*49152, off_b + l*96, aw_b + l*96,
        offaw, nullptr, nullptr, MROW, 192, 256, 192);
    val_gemm<<<dim3(448, 2), dim3(512), 0, stream>>>(
        srcbf, wbf + W_VAL + (long)l*65536, val_b + l*256, valbf, pmask);
    sample_kernel<<<dim3(MROW), dim3(256), 0, stream>>>(
        valbf, 256, offaw, refin, tlens, lstart, cabf);
    g64(stream, 0, cabf, wbf + W_OUTP + (long)l*65536, outp_b + l*256, nullptr,
        tmpf, nullptr, nullptr, MROW, 256, 256, 256);
    ln_kernel<<<dim3(MROW), dim3(256), 0, stream>>>(out, tmpf, n2_g + l*256, n2_b + l*256,
                                                    out, outbf, nullptr, nullptr);
    g64(stream, 1, outbf, wbf + W_FFN1 + (long)l*262144, ffn_b1 + l*1024, nullptr,
        nullptr, ffnhbf, nullptr, MROW, 1024, 256, 1024);
    g64(stream, 0, ffnhbf, wbf + W_FFN2 + (long)l*262144, ffn_b2 + l*256, nullptr,
        tmpf, nullptr, nullptr, MROW, 256, 1024, 256);
    float* of = (l == NLAY-1) ? (float*)d_out : out;
    ln_kernel<<<dim3(MROW), dim3(256), 0, stream>>>(out, tmpf, n3_g + l*256, n3_b + l*256,
                                                    of, outbf, nullptr, nullptr);
  }
}

// Round 17
// 929.439 us; speedup vs baseline: 1.3021x; 1.0390x over previous
//
#include <hip/hip_runtime.h>
#include <cstdint>

#define NB   16
#define LQN  300
#define DM   256
#define NH   8
#define DH   32
#define NLV  3
#define DFFN 1024
#define NLAY 6
#define TT   7168
#define MROW (NB*LQN)   // 4800
#define SROW (NB*TT)    // 114688

typedef __attribute__((ext_vector_type(8))) short bf16x8;
typedef __attribute__((ext_vector_type(4))) float f32x4;

__device__ __forceinline__ float bf2f(short u) {
  unsigned x = ((unsigned)(unsigned short)u) << 16;
  return __builtin_bit_cast(float, x);
}
__device__ __forceinline__ short f2bf(float f) {
  unsigned u = __builtin_bit_cast(unsigned, f);
  u += 0x7fffu + ((u >> 16) & 1u);   // RNE
  return (short)(u >> 16);
}
__device__ __forceinline__ void load_lds16(const void* g, void* l) {
  __builtin_amdgcn_global_load_lds(
      (const __attribute__((address_space(1))) unsigned int*)g,
      (__attribute__((address_space(3))) unsigned int*)l, 16, 0, 0);
}
#define MFMA(a,b,c) __builtin_amdgcn_mfma_f32_16x16x32_bf16((a),(b),(c),0,0,0)

// ---------------- weight + src fp32->bf16 conversion ----------------
struct CvtPtrs { const float* p[13]; };

__global__ __launch_bounds__(256)
void cvt_all_kernel(CvtPtrs ptrs, short* __restrict__ dst)
{
  const long gid = (long)blockIdx.x*256 + threadIdx.x;  // float4 units
  const long cums[14] = {0,32768,49152,65536,81920,376832,475136,512000,
                         548864,647168,745472,1138688,1531904,8871936};
  int s = 0;
  #pragma unroll
  for (int i = 1; i < 13; ++i) s += (gid >= cums[i]) ? 1 : 0;
  const long rel = gid - cums[s];
  const float4 v = ((const float4*)ptrs.p[s])[rel];
  long dstIdx = gid;
  if (s == 6) { const long l = rel/6144, w = rel%6144; dstIdx = 475136 + l*12288 + w; }
  else if (s == 7) { const long l = rel/6144, w = rel%6144; dstIdx = 475136 + l*12288 + 6144 + w; }
  ((short4*)dst)[dstIdx] = make_short4(f2bf(v.x), f2bf(v.y), f2bf(v.z), f2bf(v.w));
}

#define VLS 264   // padded LDS row stride (shorts)

// ---------------- val projection: BC=128 streaming GEMM, 2 blocks/CU (R13-proven) ----------------
__global__ __launch_bounds__(512, 2)
void val_gemm(const short* __restrict__ srcbf, const short* __restrict__ Bw,
              const float* __restrict__ bias, short* __restrict__ Cb,
              const unsigned char* __restrict__ rowmask)
{
  __shared__ short Bs[128*VLS];   // 67,584 B
  const int tid = threadIdx.x, wid = tid >> 6, lane = tid & 63;
  const int fr = lane & 15, fq = lane >> 4;
  const int coff = blockIdx.y * 128;

  for (int t = tid; t < 4096; t += 512) {
    const int row = t >> 5, ch = t & 31;
    const int chs = ch ^ ((row >> 4) & 7);
    *(bf16x8*)&Bs[row*VLS + chs*8] = *(const bf16x8*)(Bw + (long)(coff + row)*256 + ch*8);
  }
  __syncthreads();

  float bv[8];
  #pragma unroll
  for (int j = 0; j < 2; ++j)
    *(float4*)&bv[j*4] = *(const float4*)(bias + coff + fr*8 + j*4);

  const int rbase = (blockIdx.x*8 + wid) * 32;   // 448*8 = 3584 = SROW/32

  bf16x8 ac0, ac1, an0, an1;
  ac0 = *(const bf16x8*)(srcbf + (long)(rbase + fr)*256 + fq*8);
  ac1 = *(const bf16x8*)(srcbf + (long)(rbase + 16 + fr)*256 + fq*8);

  f32x4 acc[2][8] = {};
  #pragma unroll
  for (int ks = 0; ks < 8; ++ks) {
    if (ks < 7) {
      an0 = *(const bf16x8*)(srcbf + (long)(rbase + fr)*256 + (ks+1)*32 + fq*8);
      an1 = *(const bf16x8*)(srcbf + (long)(rbase + 16 + fr)*256 + (ks+1)*32 + fq*8);
    }
    #pragma unroll
    for (int nt = 0; nt < 8; ++nt) {
      const int row = fr*8 + nt;
      const bf16x8 b = *(const bf16x8*)&Bs[row*VLS + (((ks*4 + fq) ^ ((row >> 4) & 7)))*8];
      acc[0][nt] = MFMA(ac0, b, acc[0][nt]);
      acc[1][nt] = MFMA(ac1, b, acc[1][nt]);
    }
    if (ks < 7) { ac0 = an0; ac1 = an1; }
  }

  #pragma unroll
  for (int h = 0; h < 2; ++h) {
    #pragma unroll
    for (int r = 0; r < 4; ++r) {
      const int grow = rbase + h*16 + fq*4 + r;
      const float msc = rowmask[grow] ? 0.0f : 1.0f;
      bf16x8 o;
      #pragma unroll
      for (int j = 0; j < 8; ++j) o[j] = f2bf((acc[h][j][r] + bv[j]) * msc);
      *(bf16x8*)(Cb + (long)grow*256 + coff + fr*8) = o;
    }
  }
}

// ---------------- GEMM 64x64 tile, A[M,K] @ B[N,K]^T + bias (R3-proven) ----------------
// EPI: 0 plain, 1 relu->Cb, 2 qpos, 4 two-bias->Cf
template<int EPI>
__global__ __launch_bounds__(256)
void gemm64(const short* __restrict__ A, const short* __restrict__ B,
            const float* __restrict__ bias, const float* __restrict__ bias2,
            float* __restrict__ Cf, short* __restrict__ Cb, short* __restrict__ Cb2,
            int M, int N, int K, int ldc,
            const float* __restrict__ rawq, const float* __restrict__ resid)
{
  __shared__ short As[2][64*64];
  __shared__ short Bs[2][64*64];
  const int tid = threadIdx.x, wid = tid >> 6, lane = tid & 63;
  const int wr = wid >> 1, wc = wid & 1;
  const int fr = lane & 15, fq = lane >> 4;
  const int bm = blockIdx.x, bn = blockIdx.y;
  const int lrow = lane >> 3;
  const int schk = ((lane & 7) ^ lrow) * 8;
  const int nk = K >> 6;

  f32x4 acc[2][2] = {};

  auto stg = [&](int kt, int bsel) {
    const int k0 = kt << 6;
    #pragma unroll
    for (int i = 0; i < 2; ++i) {
      const int rr = wid*16 + i*8 + lrow;
      load_lds16(A + (long)(bm*64 + rr)*K + k0 + schk, &As[bsel][(wid*16 + i*8)*64]);
      load_lds16(B + (long)(bn*64 + rr)*K + k0 + schk, &Bs[bsel][(wid*16 + i*8)*64]);
    }
  };

  stg(0, 0);
  for (int t = 0; t < nk; ++t) {
    const int cur = t & 1;
    if (t + 1 < nk) {
      stg(t + 1, cur ^ 1);
      asm volatile("s_waitcnt vmcnt(4)" ::: "memory");
    } else {
      asm volatile("s_waitcnt vmcnt(0)" ::: "memory");
    }
    __builtin_amdgcn_s_barrier();
    __builtin_amdgcn_sched_barrier(0);
    #pragma unroll
    for (int kk = 0; kk < 64; kk += 32) {
      bf16x8 af[2], bv[2];
      #pragma unroll
      for (int mi = 0; mi < 2; ++mi)
        af[mi] = *(const bf16x8*)&As[cur][(wr*32 + mi*16 + fr)*64 + (((kk>>3)+fq) ^ (fr&7))*8];
      #pragma unroll
      for (int ni = 0; ni < 2; ++ni)
        bv[ni] = *(const bf16x8*)&Bs[cur][(wc*32 + ni*16 + fr)*64 + (((kk>>3)+fq) ^ (fr&7))*8];
      #pragma unroll
      for (int mi = 0; mi < 2; ++mi)
        #pragma unroll
        for (int ni = 0; ni < 2; ++ni)
          acc[mi][ni] = MFMA(af[mi], bv[ni], acc[mi][ni]);
    }
    __builtin_amdgcn_s_barrier();
  }

  #pragma unroll
  for (int mi = 0; mi < 2; ++mi) {
    #pragma unroll
    for (int r = 0; r < 4; ++r) {
      const int grow = bm*64 + wr*32 + mi*16 + fq*4 + r;
      #pragma unroll
      for (int ni = 0; ni < 2; ++ni) {
        const int gcol = bn*64 + wc*32 + ni*16 + fr;
        float v = acc[mi][ni][r];
        if (EPI == 4) v += (gcol < 96) ? bias[gcol] : bias2[gcol-96];
        else v += bias[gcol];
        const long off = (long)grow*ldc + gcol;
        if (EPI == 0) {
          if (Cf) Cf[off] = v;
          if (Cb) Cb[off] = f2bf(v);
        } else if (EPI == 1) {
          Cb[off] = f2bf(fmaxf(v, 0.0f));
        } else if (EPI == 2) {
          const float qp = v * rawq[off];
          Cf[off] = qp;
          Cb[off] = f2bf(resid[off] + qp);
        } else if (EPI == 4) {
          Cf[off] = v;
        }
      }
    }
  }
}

// ---------------- out = tgt (f32 + bf16 copies) ----------------
__global__ __launch_bounds__(256)
void ew0_kernel(const float* __restrict__ tgt, float* __restrict__ out, short* __restrict__ outbf)
{
  const long i = (long)blockIdx.x*256 + threadIdx.x;
  const float4 v = ((const float4*)tgt)[i];
  ((float4*)out)[i] = v;
  ((short4*)outbf)[i] = make_short4(f2bf(v.x), f2bf(v.y), f2bf(v.z), f2bf(v.w));
}

// ---------------- ref / ref_in / sine embedding ----------------
__global__ __launch_bounds__(256)
void init_ref_kernel(const float* __restrict__ seg, const float* __restrict__ dur,
                     const float* __restrict__ valid,
                     short* __restrict__ sinebf, float* __restrict__ refin)
{
  const int m = blockIdx.x;
  const int n = m / LQN;
  const int t = threadIdx.x;
  const float c = seg[(long)m*2 + 0];
  const float w = __expf(seg[(long)m*2 + 1]);
  const float e = (float)(t & ~1) * (1.0f/256.0f);
  const float invdim = __expf(-e * 9.2103403719761836f);
  const float twopi = 6.2831853071795864f;
  const float a0 = c * twopi * invdim;
  const float a1 = w * twopi * invdim;
  const float v0 = (t & 1) ? cosf(a0) : sinf(a0);
  const float v1 = (t & 1) ? cosf(a1) : sinf(a1);
  sinebf[(long)m*512 + t]       = f2bf(v0);
  sinebf[(long)m*512 + 256 + t] = f2bf(v1);
  if (t < 6) {
    const int l = t >> 1, cc = t & 1;
    const float rv = cc ? w : c;
    refin[(long)m*6 + l*2 + cc] = rv / dur[n] * valid[n*NLV + l];
  }
}

// ---------------- MFMA attention ----------------
#define KPAD 320
#define KSTR 40
#define VSTR 328
#define PSTR 328

__global__ __launch_bounds__(256)
void attn_mfma(const short* __restrict__ qk, const short* __restrict__ vv,
               short* __restrict__ outb)
{
  __shared__ short Kl[KPAD*KSTR];
  __shared__ short Vt[DH*VSTR];
  __shared__ short Pl[4][16*PSTR];
  const int b = blockIdx.x;
  const int half = b & 1, h = (b >> 1) & 7, n = b >> 4;
  const int tid = threadIdx.x, wid = tid >> 6, lane = tid & 63;
  const int fr = lane & 15, fq = lane >> 4;

  const short* qkn = qk + (long)n*LQN*512;
  const short* vn  = vv + (long)n*LQN*256;

  for (int t = tid; t < KPAD*4; t += 256) {
    const int r = t >> 2, c = t & 3;
    bf16x8 kv = {}, vw = {};
    if (r < LQN) {
      kv = *(const bf16x8*)(qkn + (long)r*512 + 256 + h*32 + c*8);
      vw = *(const bf16x8*)(vn  + (long)r*256 + h*32 + c*8);
    }
    *(bf16x8*)&Kl[r*KSTR + c*8] = kv;
    #pragma unroll
    for (int j = 0; j < 8; ++j) Vt[(c*8+j)*VSTR + r] = vw[j];
  }
  for (int t = tid; t < 4*16*24; t += 256) {
    const int w = t / (16*24), rr = (t / 24) & 15, cc = t % 24;
    Pl[w][rr*PSTR + 304 + cc] = 0;
  }
  __syncthreads();

  const int tlo = half ? 10 : 0, thi = half ? 19 : 10;
  const float scl2 = 0.17677669529663687f * 1.4426950408889634f;

  for (int qt = tlo + wid; qt < thi; qt += 4) {
    const int q0 = qt * 16;
    const int qrow = min(q0 + fr, LQN-1);
    const bf16x8 qf = *(const bf16x8*)(qkn + (long)qrow*512 + h*32 + fq*8);
    f32x4 s[19];
    #pragma unroll
    for (int t = 0; t < 19; ++t) {
      const bf16x8 kf = *(const bf16x8*)&Kl[(t*16+fr)*KSTR + fq*8];
      s[t] = MFMA(qf, kf, ((f32x4){0.f,0.f,0.f,0.f}));
    }
    float mx[4] = {-3e38f,-3e38f,-3e38f,-3e38f};
    #pragma unroll
    for (int t = 0; t < 19; ++t) {
      const bool valid = (t < 18) || (fr < 12);
      #pragma unroll
      for (int r = 0; r < 4; ++r) if (valid) mx[r] = fmaxf(mx[r], s[t][r]);
    }
    #pragma unroll
    for (int r = 0; r < 4; ++r) {
      #pragma unroll
      for (int o = 1; o < 16; o <<= 1) mx[r] = fmaxf(mx[r], __shfl_xor(mx[r], o));
      mx[r] *= scl2;
    }
    float l[4] = {0.f,0.f,0.f,0.f};
    #pragma unroll
    for (int t = 0; t < 19; ++t) {
      const bool valid = (t < 18) || (fr < 12);
      #pragma unroll
      for (int r = 0; r < 4; ++r) {
        const float p = valid ? exp2f(s[t][r]*scl2 - mx[r]) : 0.0f;
        l[r] += p;
        Pl[wid][(fq*4+r)*PSTR + t*16 + fr] = f2bf(p);
      }
    }
    #pragma unroll
    for (int r = 0; r < 4; ++r) {
      #pragma unroll
      for (int o = 1; o < 16; o <<= 1) l[r] += __shfl_xor(l[r], o);
    }
    f32x4 o0 = {}, o1 = {};
    #pragma unroll
    for (int ck = 0; ck < 10; ++ck) {
      const bf16x8 pf = *(const bf16x8*)&Pl[wid][fr*PSTR + ck*32 + fq*8];
      const bf16x8 v0 = *(const bf16x8*)&Vt[fr*VSTR + ck*32 + fq*8];
      const bf16x8 v1 = *(const bf16x8*)&Vt[(16+fr)*VSTR + ck*32 + fq*8];
      o0 = MFMA(pf, v0, o0);
      o1 = MFMA(pf, v1, o1);
    }
    #pragma unroll
    for (int r = 0; r < 4; ++r) {
      const int qq = q0 + fq*4 + r;
      if (qq < LQN) {
        const float inv = 1.0f / l[r];
        outb[((long)(n*LQN+qq))*256 + h*32 + fr]      = f2bf(o0[r]*inv);
        outb[((long)(n*LQN+qq))*256 + h*32 + 16 + fr] = f2bf(o1[r]*inv);
      }
    }
  }
}

// ---------------- residual + LayerNorm, 4 rows/block, wave-local reduce ----------------
__global__ __launch_bounds__(256)
void ln4_kernel(const float* __restrict__ resid, const float* __restrict__ delta,
                const float* __restrict__ g, const float* __restrict__ b,
                float* __restrict__ of, short* __restrict__ ob,
                const float* __restrict__ qpos, short* __restrict__ caqb)
{
  const int tid = threadIdx.x, wid = tid >> 6, lane = tid & 63;
  const int m = blockIdx.x*4 + wid;
  const long base = (long)m*DM + lane*4;

  const float4 xr = *(const float4*)(resid + base);
  const float4 xd = *(const float4*)(delta + base);
  float x[4] = {xr.x+xd.x, xr.y+xd.y, xr.z+xd.z, xr.w+xd.w};

  float s  = x[0]+x[1]+x[2]+x[3];
  float s2 = x[0]*x[0]+x[1]*x[1]+x[2]*x[2]+x[3]*x[3];
  #pragma unroll
  for (int o = 1; o < 64; o <<= 1) { s += __shfl_xor(s, o); s2 += __shfl_xor(s2, o); }

  const float mean = s * (1.0f/DM);
  const float var  = s2 * (1.0f/DM) - mean*mean;
  const float rst  = rsqrtf(var + 1e-5f);

  const float4 gv = *(const float4*)(g + lane*4);
  const float4 bv = *(const float4*)(b + lane*4);
  float y[4];
  y[0] = (x[0]-mean)*rst*gv.x + bv.x;
  y[1] = (x[1]-mean)*rst*gv.y + bv.y;
  y[2] = (x[2]-mean)*rst*gv.z + bv.z;
  y[3] = (x[3]-mean)*rst*gv.w + bv.w;

  *(float4*)(of + base) = make_float4(y[0], y[1], y[2], y[3]);
  *(short4*)(ob + base) = make_short4(f2bf(y[0]), f2bf(y[1]), f2bf(y[2]), f2bf(y[3]));
  if (qpos) {
    const float4 qv = *(const float4*)(qpos + base);
    *(short4*)(caqb + base) = make_short4(f2bf(y[0]+qv.x), f2bf(y[1]+qv.y),
                                          f2bf(y[2]+qv.z), f2bf(y[3]+qv.w));
  }
}

// ---------------- sampling: fused prep (softmax+bilinear) + gather-MAC ----------------
__global__ __launch_bounds__(256)
void sample_kernel(const short* __restrict__ val, int ldv,
                   const float* __restrict__ offaw, const float* __restrict__ refin,
                   const int* __restrict__ tlens, const int* __restrict__ lstart,
                   short* __restrict__ cab)
{
  const int m = blockIdx.x;
  const int n = m / LQN;
  const int tid = threadIdx.x;
  __shared__ int2  lI[96];
  __shared__ float2 lW[96];
  if ((tid & 31) == 0) {
    const int h = tid >> 5;
    const float* row = offaw + (long)m*192;
    float aw[12];
    float mx = -1e30f;
    #pragma unroll
    for (int lp = 0; lp < 12; ++lp) { aw[lp] = row[96 + h*12 + lp]; mx = fmaxf(mx, aw[lp]); }
    float sum = 0.0f;
    #pragma unroll
    for (int lp = 0; lp < 12; ++lp) { aw[lp] = __expf(aw[lp]-mx); sum += aw[lp]; }
    const float invs = 1.0f / sum;
    #pragma unroll
    for (int lp = 0; lp < 12; ++lp) {
      const int l = lp >> 2;
      const int tli = tlens[l];
      const float off = row[h*12 + lp];
      const float loc = refin[(long)m*6 + l*2] + off * 0.25f * refin[(long)m*6 + l*2 + 1] * 0.5f;
      const float x = loc * (float)tli - 0.5f;
      const float x0f = floorf(x);
      const float f = x - x0f;
      const int x0 = (int)x0f;
      const int i0 = lstart[l] + min(max(x0,   0), tli-1);
      const int i1 = lstart[l] + min(max(x0+1, 0), tli-1);
      const float wgt = aw[lp]*invs;
      const float w0 = (x0   >= 0 && x0   < tli) ? wgt*(1.0f-f) : 0.0f;
      const float w1 = (x0+1 >= 0 && x0+1 < tli) ? wgt*f        : 0.0f;
      lI[h*12 + lp] = make_int2(i0, i1);
      lW[h*12 + lp] = make_float2(w0, w1);
    }
  }
  __syncthreads();
  const int h = tid >> 5;
  const short* vb = val + (long)n*TT*ldv;
  float acc = 0.0f;
  #pragma unroll
  for (int lp = 0; lp < 12; ++lp) {
    const int e = h*12 + lp;
    const int2 ii = lI[e];
    const float2 ww = lW[e];
    acc += ww.x * bf2f(vb[(long)ii.x*ldv + tid]) + ww.y * bf2f(vb[(long)ii.y*ldv + tid]);
  }
  cab[(long)m*DM + tid] = f2bf(acc);
}

// ---------------- host side ----------------
static inline void g64(hipStream_t st, int epi, const short* A, const short* B,
                       const float* bias, const float* bias2,
                       float* Cf, short* Cb, short* Cb2,
                       int M, int N, int K, int ldc,
                       const float* rawq = nullptr, const float* resid = nullptr)
{
  dim3 g(M/64, N/64), blk(256);
  switch (epi) {
    case 0: gemm64<0><<<g,blk,0,st>>>(A,B,bias,bias2,Cf,Cb,Cb2,M,N,K,ldc,rawq,resid); break;
    case 1: gemm64<1><<<g,blk,0,st>>>(A,B,bias,bias2,Cf,Cb,Cb2,M,N,K,ldc,rawq,resid); break;
    case 2: gemm64<2><<<g,blk,0,st>>>(A,B,bias,bias2,Cf,Cb,Cb2,M,N,K,ldc,rawq,resid); break;
    default:gemm64<4><<<g,blk,0,st>>>(A,B,bias,bias2,Cf,Cb,Cb2,M,N,K,ldc,rawq,resid); break;
  }
}

extern "C" void kernel_launch(void* const* d_in, const int* in_sizes, int n_in,
                              void* d_out, int out_size, void* d_ws, size_t ws_size,
                              hipStream_t stream)
{
  const float* tgt    = (const float*)d_in[0];
  const float* seg    = (const float*)d_in[1];
  const float* dur    = (const float*)d_in[2];
  const float* src    = (const float*)d_in[3];
  const int*   tlens  = (const int*)d_in[4];
  const int*   lstart = (const int*)d_in[5];
  const float* valid  = (const float*)d_in[6];
  const unsigned char* pmask = (const unsigned char*)d_in[7];
  const float* grid_w0 = (const float*)d_in[8];
  const float* grid_b0 = (const float*)d_in[9];
  const float* grid_w1 = (const float*)d_in[10];
  const float* grid_b1 = (const float*)d_in[11];
  const float* qs_w0 = (const float*)d_in[12];
  const float* qs_b0 = (const float*)d_in[13];
  const float* qs_w1 = (const float*)d_in[14];
  const float* qs_b1 = (const float*)d_in[15];
  const float* sa_in_w  = (const float*)d_in[16];
  const float* sa_in_b  = (const float*)d_in[17];
  const float* sa_out_w = (const float*)d_in[18];
  const float* sa_out_b = (const float*)d_in[19];
  const float* n1_g = (const float*)d_in[20];
  const float* n1_b = (const float*)d_in[21];
  const float* n2_g = (const float*)d_in[22];
  const float* n2_b = (const float*)d_in[23];
  const float* n3_g = (const float*)d_in[24];
  const float* n3_b = (const float*)d_in[25];
  const float* off_w = (const float*)d_in[26];
  const float* off_b = (const float*)d_in[27];
  const float* aw_w  = (const float*)d_in[28];
  const float* aw_b  = (const float*)d_in[29];
  const float* val_w = (const float*)d_in[30];
  const float* val_b = (const float*)d_in[31];
  const float* outp_w = (const float*)d_in[32];
  const float* outp_b = (const float*)d_in[33];
  const float* ffn_w1 = (const float*)d_in[34];
  const float* ffn_b1 = (const float*)d_in[35];
  const float* ffn_w2 = (const float*)d_in[36];
  const float* ffn_b2 = (const float*)d_in[37];

  // bf16 weight region offsets (shorts); src bf16 follows weights
  const long W_G0=0, W_G1=131072, W_QS0=196608, W_QS1=262144, W_SAIN=327680,
             W_SAOUT=1507328, W_OFFAW=1900544, W_VAL=2195456,
             W_OUTP=2588672, W_FFN1=2981888, W_FFN2=4554752, W_SRC=6127616;

  char* ws = (char*)d_ws;
  short* wbf    = (short*)(ws + 0);
  short* srcbf  = wbf + W_SRC;
  short* sinebf = (short*)(ws + 70975488);
  short* ghbf   = (short*)(ws + 75890688);
  float* rawq   = (float*)(ws + 78348288);
  float* out    = (float*)(ws + 83263488);
  short* qbf    = (short*)(ws + 88178688);
  short* outbf  = qbf + (long)MROW*DM;
  short* t1bf   = (short*)(ws + 93093888);
  float* qpos   = (float*)(ws + 95551488);
  short* qkbf   = (short*)(ws + 100466688);   // [4800][512]
  short* vbf    = (short*)(ws + 105381888);   // [4800][256]
  short* attnbf = (short*)(ws + 107839488);
  float* tmpf   = (float*)(ws + 110297088);
  short* caqb   = (short*)(ws + 115212288);
  float* offaw  = (float*)(ws + 117669888);   // [4800][192]
  short* cabf   = (short*)(ws + 128729088);
  short* ffnhbf = (short*)(ws + 131186688);
  float* refin  = (float*)(ws + 141017088);
  short* valbf  = (short*)(ws + 141132288);   // [114688][256]

  CvtPtrs cp;
  cp.p[0]=grid_w0; cp.p[1]=grid_w1; cp.p[2]=qs_w0; cp.p[3]=qs_w1; cp.p[4]=sa_in_w;
  cp.p[5]=sa_out_w; cp.p[6]=off_w; cp.p[7]=aw_w; cp.p[8]=val_w; cp.p[9]=outp_w;
  cp.p[10]=ffn_w1; cp.p[11]=ffn_w2; cp.p[12]=src;
  cvt_all_kernel<<<dim3(34656), dim3(256), 0, stream>>>(cp, wbf);

  ew0_kernel<<<dim3(1200), dim3(256), 0, stream>>>(tgt, out, outbf);
  init_ref_kernel<<<dim3(MROW), dim3(256), 0, stream>>>(seg, dur, valid, sinebf, refin);

  g64(stream, 1, sinebf, wbf + W_G0, grid_b0, nullptr, nullptr, ghbf, nullptr, MROW, 256, 512, 256);
  g64(stream, 0, ghbf,   wbf + W_G1, grid_b1, nullptr, rawq, nullptr, nullptr, MROW, 256, 256, 256);

  for (int l = 0; l < NLAY; ++l) {
    g64(stream, 1, outbf, wbf + W_QS0, qs_b0, nullptr, nullptr, t1bf, nullptr, MROW, 256, 256, 256);
    g64(stream, 2, t1bf,  wbf + W_QS1, qs_b1, nullptr, qpos, qbf, nullptr, MROW, 256, 256, 256,
        rawq, out);
    // self-attn projections split: qk from qbf (N=512), v from outbf (N=256)
    g64(stream, 0, qbf, wbf + W_SAIN + (long)l*196608, sa_in_b + l*768, nullptr,
        nullptr, qkbf, nullptr, MROW, 512, 256, 512);
    g64(stream, 0, outbf, wbf + W_SAIN + (long)l*196608 + 131072, sa_in_b + l*768 + 512, nullptr,
        nullptr, vbf, nullptr, MROW, 256, 256, 256);
    attn_mfma<<<dim3(256), dim3(256), 0, stream>>>(qkbf, vbf, attnbf);
    g64(stream, 0, attnbf, wbf + W_SAOUT + (long)l*65536, sa_out_b + l*256, nullptr,
        tmpf, nullptr, nullptr, MROW, 256, 256, 256);
    ln4_kernel<<<dim3(MROW/4), dim3(256), 0, stream>>>(out, tmpf, n1_g + l*256, n1_b + l*256,
                                                       out, outbf, qpos, caqb);
    g64(stream, 4, caqb, wbf + W_OFFAW + (long)l*49152, off_b + l*96, aw_b + l*96,
        offaw, nullptr, nullptr, MROW, 192, 256, 192);
    val_gemm<<<dim3(448, 2), dim3(512), 0, stream>>>(
        srcbf, wbf + W_VAL + (long)l*65536, val_b + l*256, valbf, pmask);
    sample_kernel<<<dim3(MROW), dim3(256), 0, stream>>>(
        valbf, 256, offaw, refin, tlens, lstart, cabf);
    g64(stream, 0, cabf, wbf + W_OUTP + (long)l*65536, outp_b + l*256, nullptr,
        tmpf, nullptr, nullptr, MROW, 256, 256, 256);
    ln4_kernel<<<dim3(MROW/4), dim3(256), 0, stream>>>(out, tmpf, n2_g + l*256, n2_b + l*256,
                                                       out, outbf, nullptr, nullptr);
    g64(stream, 1, outbf, wbf + W_FFN1 + (long)l*262144, ffn_b1 + l*1024, nullptr,
        nullptr, ffnhbf, nullptr, MROW, 1024, 256, 1024);
    g64(stream, 0, ffnhbf, wbf + W_FFN2 + (long)l*262144, ffn_b2 + l*256, nullptr,
        tmpf, nullptr, nullptr, MROW, 256, 1024, 256);
    float* of = (l == NLAY-1) ? (float*)d_out : out;
    ln4_kernel<<<dim3(MROW/4), dim3(256), 0, stream>>>(out, tmpf, n3_g + l*256, n3_b + l*256,
                                                       of, outbf, nullptr, nullptr);
  }
}

// Round 18
// 922.052 us; speedup vs baseline: 1.3125x; 1.0080x over previous
//
#include <hip/hip_runtime.h>
#include <cstdint>

#define NB   16
#define LQN  300
#define DM   256
#define NH   8
#define DH   32
#define NLV  3
#define DFFN 1024
#define NLAY 6
#define TT   7168
#define MROW (NB*LQN)   // 4800
#define SROW (NB*TT)    // 114688

typedef __attribute__((ext_vector_type(8))) short bf16x8;
typedef __attribute__((ext_vector_type(4))) float f32x4;

__device__ __forceinline__ float bf2f(short u) {
  unsigned x = ((unsigned)(unsigned short)u) << 16;
  return __builtin_bit_cast(float, x);
}
__device__ __forceinline__ short f2bf(float f) {
  unsigned u = __builtin_bit_cast(unsigned, f);
  u += 0x7fffu + ((u >> 16) & 1u);   // RNE
  return (short)(u >> 16);
}
__device__ __forceinline__ void load_lds16(const void* g, void* l) {
  __builtin_amdgcn_global_load_lds(
      (const __attribute__((address_space(1))) unsigned int*)g,
      (__attribute__((address_space(3))) unsigned int*)l, 16, 0, 0);
}
#define MFMA(a,b,c) __builtin_amdgcn_mfma_f32_16x16x32_bf16((a),(b),(c),0,0,0)

// ---------------- weight + src fp32->bf16 conversion ----------------
struct CvtPtrs { const float* p[13]; };

__global__ __launch_bounds__(256)
void cvt_all_kernel(CvtPtrs ptrs, short* __restrict__ dst)
{
  const long gid = (long)blockIdx.x*256 + threadIdx.x;  // float4 units
  const long cums[14] = {0,32768,49152,65536,81920,376832,475136,512000,
                         548864,647168,745472,1138688,1531904,8871936};
  int s = 0;
  #pragma unroll
  for (int i = 1; i < 13; ++i) s += (gid >= cums[i]) ? 1 : 0;
  const long rel = gid - cums[s];
  const float4 v = ((const float4*)ptrs.p[s])[rel];
  long dstIdx = gid;
  if (s == 6) { const long l = rel/6144, w = rel%6144; dstIdx = 475136 + l*12288 + w; }
  else if (s == 7) { const long l = rel/6144, w = rel%6144; dstIdx = 475136 + l*12288 + 6144 + w; }
  ((short4*)dst)[dstIdx] = make_short4(f2bf(v.x), f2bf(v.y), f2bf(v.z), f2bf(v.w));
}

#define VLS 264   // padded LDS row stride (shorts)

// ---------------- val projection: BC=128 streaming GEMM, 2 blocks/CU (R13-proven) ----------------
__global__ __launch_bounds__(512, 2)
void val_gemm(const short* __restrict__ srcbf, const short* __restrict__ Bw,
              const float* __restrict__ bias, short* __restrict__ Cb,
              const unsigned char* __restrict__ rowmask)
{
  __shared__ short Bs[128*VLS];   // 67,584 B
  const int tid = threadIdx.x, wid = tid >> 6, lane = tid & 63;
  const int fr = lane & 15, fq = lane >> 4;
  const int coff = blockIdx.y * 128;

  for (int t = tid; t < 4096; t += 512) {
    const int row = t >> 5, ch = t & 31;
    const int chs = ch ^ ((row >> 4) & 7);
    *(bf16x8*)&Bs[row*VLS + chs*8] = *(const bf16x8*)(Bw + (long)(coff + row)*256 + ch*8);
  }
  __syncthreads();

  float bv[8];
  #pragma unroll
  for (int j = 0; j < 2; ++j)
    *(float4*)&bv[j*4] = *(const float4*)(bias + coff + fr*8 + j*4);

  const int rbase = (blockIdx.x*8 + wid) * 32;   // 448*8 = 3584 = SROW/32

  bf16x8 ac0, ac1, an0, an1;
  ac0 = *(const bf16x8*)(srcbf + (long)(rbase + fr)*256 + fq*8);
  ac1 = *(const bf16x8*)(srcbf + (long)(rbase + 16 + fr)*256 + fq*8);

  f32x4 acc[2][8] = {};
  #pragma unroll
  for (int ks = 0; ks < 8; ++ks) {
    if (ks < 7) {
      an0 = *(const bf16x8*)(srcbf + (long)(rbase + fr)*256 + (ks+1)*32 + fq*8);
      an1 = *(const bf16x8*)(srcbf + (long)(rbase + 16 + fr)*256 + (ks+1)*32 + fq*8);
    }
    #pragma unroll
    for (int nt = 0; nt < 8; ++nt) {
      const int row = fr*8 + nt;
      const bf16x8 b = *(const bf16x8*)&Bs[row*VLS + (((ks*4 + fq) ^ ((row >> 4) & 7)))*8];
      acc[0][nt] = MFMA(ac0, b, acc[0][nt]);
      acc[1][nt] = MFMA(ac1, b, acc[1][nt]);
    }
    if (ks < 7) { ac0 = an0; ac1 = an1; }
  }

  #pragma unroll
  for (int h = 0; h < 2; ++h) {
    #pragma unroll
    for (int r = 0; r < 4; ++r) {
      const int grow = rbase + h*16 + fq*4 + r;
      const float msc = rowmask[grow] ? 0.0f : 1.0f;
      bf16x8 o;
      #pragma unroll
      for (int j = 0; j < 8; ++j) o[j] = f2bf((acc[h][j][r] + bv[j]) * msc);
      *(bf16x8*)(Cb + (long)grow*256 + coff + fr*8) = o;
    }
  }
}

// ---------------- GEMM 64x64 tile, A[M,K] @ B[N,K]^T + bias (R3-proven) ----------------
// EPI: 0 plain, 1 relu->Cb, 2 qpos, 4 two-bias->Cf
template<int EPI>
__global__ __launch_bounds__(256)
void gemm64(const short* __restrict__ A, const short* __restrict__ B,
            const float* __restrict__ bias, const float* __restrict__ bias2,
            float* __restrict__ Cf, short* __restrict__ Cb, short* __restrict__ Cb2,
            int M, int N, int K, int ldc,
            const float* __restrict__ rawq, const float* __restrict__ resid)
{
  __shared__ short As[2][64*64];
  __shared__ short Bs[2][64*64];
  const int tid = threadIdx.x, wid = tid >> 6, lane = tid & 63;
  const int wr = wid >> 1, wc = wid & 1;
  const int fr = lane & 15, fq = lane >> 4;
  const int bm = blockIdx.x, bn = blockIdx.y;
  const int lrow = lane >> 3;
  const int schk = ((lane & 7) ^ lrow) * 8;
  const int nk = K >> 6;

  f32x4 acc[2][2] = {};

  auto stg = [&](int kt, int bsel) {
    const int k0 = kt << 6;
    #pragma unroll
    for (int i = 0; i < 2; ++i) {
      const int rr = wid*16 + i*8 + lrow;
      load_lds16(A + (long)(bm*64 + rr)*K + k0 + schk, &As[bsel][(wid*16 + i*8)*64]);
      load_lds16(B + (long)(bn*64 + rr)*K + k0 + schk, &Bs[bsel][(wid*16 + i*8)*64]);
    }
  };

  stg(0, 0);
  for (int t = 0; t < nk; ++t) {
    const int cur = t & 1;
    if (t + 1 < nk) {
      stg(t + 1, cur ^ 1);
      asm volatile("s_waitcnt vmcnt(4)" ::: "memory");
    } else {
      asm volatile("s_waitcnt vmcnt(0)" ::: "memory");
    }
    __builtin_amdgcn_s_barrier();
    __builtin_amdgcn_sched_barrier(0);
    #pragma unroll
    for (int kk = 0; kk < 64; kk += 32) {
      bf16x8 af[2], bv[2];
      #pragma unroll
      for (int mi = 0; mi < 2; ++mi)
        af[mi] = *(const bf16x8*)&As[cur][(wr*32 + mi*16 + fr)*64 + (((kk>>3)+fq) ^ (fr&7))*8];
      #pragma unroll
      for (int ni = 0; ni < 2; ++ni)
        bv[ni] = *(const bf16x8*)&Bs[cur][(wc*32 + ni*16 + fr)*64 + (((kk>>3)+fq) ^ (fr&7))*8];
      #pragma unroll
      for (int mi = 0; mi < 2; ++mi)
        #pragma unroll
        for (int ni = 0; ni < 2; ++ni)
          acc[mi][ni] = MFMA(af[mi], bv[ni], acc[mi][ni]);
    }
    __builtin_amdgcn_s_barrier();
  }

  #pragma unroll
  for (int mi = 0; mi < 2; ++mi) {
    #pragma unroll
    for (int r = 0; r < 4; ++r) {
      const int grow = bm*64 + wr*32 + mi*16 + fq*4 + r;
      #pragma unroll
      for (int ni = 0; ni < 2; ++ni) {
        const int gcol = bn*64 + wc*32 + ni*16 + fr;
        float v = acc[mi][ni][r];
        if (EPI == 4) v += (gcol < 96) ? bias[gcol] : bias2[gcol-96];
        else v += bias[gcol];
        const long off = (long)grow*ldc + gcol;
        if (EPI == 0) {
          if (Cf) Cf[off] = v;
          if (Cb) Cb[off] = f2bf(v);
        } else if (EPI == 1) {
          Cb[off] = f2bf(fmaxf(v, 0.0f));
        } else if (EPI == 2) {
          const float qp = v * rawq[off];
          Cf[off] = qp;
          Cb[off] = f2bf(resid[off] + qp);
        } else if (EPI == 4) {
          Cf[off] = v;
        }
      }
    }
  }
}

// ---------------- fused qs0 (relu) + v-proj GEMM: same A, grid (75, 8) ----------------
// bn<4: outbf @ Bq^T + biasq, relu -> Cq ; bn>=4: outbf @ Bv^T + biasv -> Cv
__global__ __launch_bounds__(256)
void gemm64_qs0v(const short* __restrict__ A,
                 const short* __restrict__ Bq, const short* __restrict__ Bv,
                 const float* __restrict__ biasq, const float* __restrict__ biasv,
                 short* __restrict__ Cq, short* __restrict__ Cv)
{
  __shared__ short As[2][64*64];
  __shared__ short Bs[2][64*64];
  const int tid = threadIdx.x, wid = tid >> 6, lane = tid & 63;
  const int wr = wid >> 1, wc = wid & 1;
  const int fr = lane & 15, fq = lane >> 4;
  const int bm = blockIdx.x;
  const bool isv = blockIdx.y >= 4;
  const int bn = isv ? blockIdx.y - 4 : blockIdx.y;
  const short* B = isv ? Bv : Bq;
  const float* bias = isv ? biasv : biasq;
  short* Cb = isv ? Cv : Cq;
  const int lrow = lane >> 3;
  const int schk = ((lane & 7) ^ lrow) * 8;
  const int K = 256, ldc = 256, nk = 4;

  f32x4 acc[2][2] = {};

  auto stg = [&](int kt, int bsel) {
    const int k0 = kt << 6;
    #pragma unroll
    for (int i = 0; i < 2; ++i) {
      const int rr = wid*16 + i*8 + lrow;
      load_lds16(A + (long)(bm*64 + rr)*K + k0 + schk, &As[bsel][(wid*16 + i*8)*64]);
      load_lds16(B + (long)(bn*64 + rr)*K + k0 + schk, &Bs[bsel][(wid*16 + i*8)*64]);
    }
  };

  stg(0, 0);
  for (int t = 0; t < nk; ++t) {
    const int cur = t & 1;
    if (t + 1 < nk) {
      stg(t + 1, cur ^ 1);
      asm volatile("s_waitcnt vmcnt(4)" ::: "memory");
    } else {
      asm volatile("s_waitcnt vmcnt(0)" ::: "memory");
    }
    __builtin_amdgcn_s_barrier();
    __builtin_amdgcn_sched_barrier(0);
    #pragma unroll
    for (int kk = 0; kk < 64; kk += 32) {
      bf16x8 af[2], bv[2];
      #pragma unroll
      for (int mi = 0; mi < 2; ++mi)
        af[mi] = *(const bf16x8*)&As[cur][(wr*32 + mi*16 + fr)*64 + (((kk>>3)+fq) ^ (fr&7))*8];
      #pragma unroll
      for (int ni = 0; ni < 2; ++ni)
        bv[ni] = *(const bf16x8*)&Bs[cur][(wc*32 + ni*16 + fr)*64 + (((kk>>3)+fq) ^ (fr&7))*8];
      #pragma unroll
      for (int mi = 0; mi < 2; ++mi)
        #pragma unroll
        for (int ni = 0; ni < 2; ++ni)
          acc[mi][ni] = MFMA(af[mi], bv[ni], acc[mi][ni]);
    }
    __builtin_amdgcn_s_barrier();
  }

  #pragma unroll
  for (int mi = 0; mi < 2; ++mi) {
    #pragma unroll
    for (int r = 0; r < 4; ++r) {
      const int grow = bm*64 + wr*32 + mi*16 + fq*4 + r;
      #pragma unroll
      for (int ni = 0; ni < 2; ++ni) {
        const int gcol = bn*64 + wc*32 + ni*16 + fr;
        float v = acc[mi][ni][r] + bias[gcol];
        if (!isv) v = fmaxf(v, 0.0f);
        Cb[(long)grow*ldc + gcol] = f2bf(v);
      }
    }
  }
}

// ---------------- out = tgt (f32 + bf16 copies) ----------------
__global__ __launch_bounds__(256)
void ew0_kernel(const float* __restrict__ tgt, float* __restrict__ out, short* __restrict__ outbf)
{
  const long i = (long)blockIdx.x*256 + threadIdx.x;
  const float4 v = ((const float4*)tgt)[i];
  ((float4*)out)[i] = v;
  ((short4*)outbf)[i] = make_short4(f2bf(v.x), f2bf(v.y), f2bf(v.z), f2bf(v.w));
}

// ---------------- ref / ref_in / sine embedding ----------------
__global__ __launch_bounds__(256)
void init_ref_kernel(const float* __restrict__ seg, const float* __restrict__ dur,
                     const float* __restrict__ valid,
                     short* __restrict__ sinebf, float* __restrict__ refin)
{
  const int m = blockIdx.x;
  const int n = m / LQN;
  const int t = threadIdx.x;
  const float c = seg[(long)m*2 + 0];
  const float w = __expf(seg[(long)m*2 + 1]);
  const float e = (float)(t & ~1) * (1.0f/256.0f);
  const float invdim = __expf(-e * 9.2103403719761836f);
  const float twopi = 6.2831853071795864f;
  const float a0 = c * twopi * invdim;
  const float a1 = w * twopi * invdim;
  const float v0 = (t & 1) ? cosf(a0) : sinf(a0);
  const float v1 = (t & 1) ? cosf(a1) : sinf(a1);
  sinebf[(long)m*512 + t]       = f2bf(v0);
  sinebf[(long)m*512 + 256 + t] = f2bf(v1);
  if (t < 6) {
    const int l = t >> 1, cc = t & 1;
    const float rv = cc ? w : c;
    refin[(long)m*6 + l*2 + cc] = rv / dur[n] * valid[n*NLV + l];
  }
}

// ---------------- MFMA attention ----------------
#define KPAD 320
#define KSTR 40
#define VSTR 328
#define PSTR 328

__global__ __launch_bounds__(256)
void attn_mfma(const short* __restrict__ qk, const short* __restrict__ vv,
               short* __restrict__ outb)
{
  __shared__ short Kl[KPAD*KSTR];
  __shared__ short Vt[DH*VSTR];
  __shared__ short Pl[4][16*PSTR];
  const int b = blockIdx.x;
  const int half = b & 1, h = (b >> 1) & 7, n = b >> 4;
  const int tid = threadIdx.x, wid = tid >> 6, lane = tid & 63;
  const int fr = lane & 15, fq = lane >> 4;

  const short* qkn = qk + (long)n*LQN*512;
  const short* vn  = vv + (long)n*LQN*256;

  for (int t = tid; t < KPAD*4; t += 256) {
    const int r = t >> 2, c = t & 3;
    bf16x8 kv = {}, vw = {};
    if (r < LQN) {
      kv = *(const bf16x8*)(qkn + (long)r*512 + 256 + h*32 + c*8);
      vw = *(const bf16x8*)(vn  + (long)r*256 + h*32 + c*8);
    }
    *(bf16x8*)&Kl[r*KSTR + c*8] = kv;
    #pragma unroll
    for (int j = 0; j < 8; ++j) Vt[(c*8+j)*VSTR + r] = vw[j];
  }
  for (int t = tid; t < 4*16*24; t += 256) {
    const int w = t / (16*24), rr = (t / 24) & 15, cc = t % 24;
    Pl[w][rr*PSTR + 304 + cc] = 0;
  }
  __syncthreads();

  const int tlo = half ? 10 : 0, thi = half ? 19 : 10;
  const float scl2 = 0.17677669529663687f * 1.4426950408889634f;

  for (int qt = tlo + wid; qt < thi; qt += 4) {
    const int q0 = qt * 16;
    const int qrow = min(q0 + fr, LQN-1);
    const bf16x8 qf = *(const bf16x8*)(qkn + (long)qrow*512 + h*32 + fq*8);
    f32x4 s[19];
    #pragma unroll
    for (int t = 0; t < 19; ++t) {
      const bf16x8 kf = *(const bf16x8*)&Kl[(t*16+fr)*KSTR + fq*8];
      s[t] = MFMA(qf, kf, ((f32x4){0.f,0.f,0.f,0.f}));
    }
    float mx[4] = {-3e38f,-3e38f,-3e38f,-3e38f};
    #pragma unroll
    for (int t = 0; t < 19; ++t) {
      const bool valid = (t < 18) || (fr < 12);
      #pragma unroll
      for (int r = 0; r < 4; ++r) if (valid) mx[r] = fmaxf(mx[r], s[t][r]);
    }
    #pragma unroll
    for (int r = 0; r < 4; ++r) {
      #pragma unroll
      for (int o = 1; o < 16; o <<= 1) mx[r] = fmaxf(mx[r], __shfl_xor(mx[r], o));
      mx[r] *= scl2;
    }
    float l[4] = {0.f,0.f,0.f,0.f};
    #pragma unroll
    for (int t = 0; t < 19; ++t) {
      const bool valid = (t < 18) || (fr < 12);
      #pragma unroll
      for (int r = 0; r < 4; ++r) {
        const float p = valid ? exp2f(s[t][r]*scl2 - mx[r]) : 0.0f;
        l[r] += p;
        Pl[wid][(fq*4+r)*PSTR + t*16 + fr] = f2bf(p);
      }
    }
    #pragma unroll
    for (int r = 0; r < 4; ++r) {
      #pragma unroll
      for (int o = 1; o < 16; o <<= 1) l[r] += __shfl_xor(l[r], o);
    }
    f32x4 o0 = {}, o1 = {};
    #pragma unroll
    for (int ck = 0; ck < 10; ++ck) {
      const bf16x8 pf = *(const bf16x8*)&Pl[wid][fr*PSTR + ck*32 + fq*8];
      const bf16x8 v0 = *(const bf16x8*)&Vt[fr*VSTR + ck*32 + fq*8];
      const bf16x8 v1 = *(const bf16x8*)&Vt[(16+fr)*VSTR + ck*32 + fq*8];
      o0 = MFMA(pf, v0, o0);
      o1 = MFMA(pf, v1, o1);
    }
    #pragma unroll
    for (int r = 0; r < 4; ++r) {
      const int qq = q0 + fq*4 + r;
      if (qq < LQN) {
        const float inv = 1.0f / l[r];
        outb[((long)(n*LQN+qq))*256 + h*32 + fr]      = f2bf(o0[r]*inv);
        outb[((long)(n*LQN+qq))*256 + h*32 + 16 + fr] = f2bf(o1[r]*inv);
      }
    }
  }
}

// ---------------- residual + LayerNorm, 4 rows/block, wave-local reduce (R17-proven) ----------------
__global__ __launch_bounds__(256)
void ln4_kernel(const float* __restrict__ resid, const float* __restrict__ delta,
                const float* __restrict__ g, const float* __restrict__ b,
                float* __restrict__ of, short* __restrict__ ob,
                const float* __restrict__ qpos, short* __restrict__ caqb)
{
  const int tid = threadIdx.x, wid = tid >> 6, lane = tid & 63;
  const int m = blockIdx.x*4 + wid;
  const long base = (long)m*DM + lane*4;

  const float4 xr = *(const float4*)(resid + base);
  const float4 xd = *(const float4*)(delta + base);
  float x[4] = {xr.x+xd.x, xr.y+xd.y, xr.z+xd.z, xr.w+xd.w};

  float s  = x[0]+x[1]+x[2]+x[3];
  float s2 = x[0]*x[0]+x[1]*x[1]+x[2]*x[2]+x[3]*x[3];
  #pragma unroll
  for (int o = 1; o < 64; o <<= 1) { s += __shfl_xor(s, o); s2 += __shfl_xor(s2, o); }

  const float mean = s * (1.0f/DM);
  const float var  = s2 * (1.0f/DM) - mean*mean;
  const float rst  = rsqrtf(var + 1e-5f);

  const float4 gv = *(const float4*)(g + lane*4);
  const float4 bv = *(const float4*)(b + lane*4);
  float y[4];
  y[0] = (x[0]-mean)*rst*gv.x + bv.x;
  y[1] = (x[1]-mean)*rst*gv.y + bv.y;
  y[2] = (x[2]-mean)*rst*gv.z + bv.z;
  y[3] = (x[3]-mean)*rst*gv.w + bv.w;

  *(float4*)(of + base) = make_float4(y[0], y[1], y[2], y[3]);
  *(short4*)(ob + base) = make_short4(f2bf(y[0]), f2bf(y[1]), f2bf(y[2]), f2bf(y[3]));
  if (qpos) {
    const float4 qv = *(const float4*)(qpos + base);
    *(short4*)(caqb + base) = make_short4(f2bf(y[0]+qv.x), f2bf(y[1]+qv.y),
                                          f2bf(y[2]+qv.z), f2bf(y[3]+qv.w));
  }
}

// ---------------- sampling: fused prep (softmax+bilinear) + gather-MAC ----------------
__global__ __launch_bounds__(256)
void sample_kernel(const short* __restrict__ val, int ldv,
                   const float* __restrict__ offaw, const float* __restrict__ refin,
                   const int* __restrict__ tlens, const int* __restrict__ lstart,
                   short* __restrict__ cab)
{
  const int m = blockIdx.x;
  const int n = m / LQN;
  const int tid = threadIdx.x;
  __shared__ int2  lI[96];
  __shared__ float2 lW[96];
  if ((tid & 31) == 0) {
    const int h = tid >> 5;
    const float* row = offaw + (long)m*192;
    float aw[12];
    float mx = -1e30f;
    #pragma unroll
    for (int lp = 0; lp < 12; ++lp) { aw[lp] = row[96 + h*12 + lp]; mx = fmaxf(mx, aw[lp]); }
    float sum = 0.0f;
    #pragma unroll
    for (int lp = 0; lp < 12; ++lp) { aw[lp] = __expf(aw[lp]-mx); sum += aw[lp]; }
    const float invs = 1.0f / sum;
    #pragma unroll
    for (int lp = 0; lp < 12; ++lp) {
      const int l = lp >> 2;
      const int tli = tlens[l];
      const float off = row[h*12 + lp];
      const float loc = refin[(long)m*6 + l*2] + off * 0.25f * refin[(long)m*6 + l*2 + 1] * 0.5f;
      const float x = loc * (float)tli - 0.5f;
      const float x0f = floorf(x);
      const float f = x - x0f;
      const int x0 = (int)x0f;
      const int i0 = lstart[l] + min(max(x0,   0), tli-1);
      const int i1 = lstart[l] + min(max(x0+1, 0), tli-1);
      const float wgt = aw[lp]*invs;
      const float w0 = (x0   >= 0 && x0   < tli) ? wgt*(1.0f-f) : 0.0f;
      const float w1 = (x0+1 >= 0 && x0+1 < tli) ? wgt*f        : 0.0f;
      lI[h*12 + lp] = make_int2(i0, i1);
      lW[h*12 + lp] = make_float2(w0, w1);
    }
  }
  __syncthreads();
  const int h = tid >> 5;
  const short* vb = val + (long)n*TT*ldv;
  float acc = 0.0f;
  #pragma unroll
  for (int lp = 0; lp < 12; ++lp) {
    const int e = h*12 + lp;
    const int2 ii = lI[e];
    const float2 ww = lW[e];
    acc += ww.x * bf2f(vb[(long)ii.x*ldv + tid]) + ww.y * bf2f(vb[(long)ii.y*ldv + tid]);
  }
  cab[(long)m*DM + tid] = f2bf(acc);
}

// ---------------- host side ----------------
static inline void g64(hipStream_t st, int epi, const short* A, const short* B,
                       const float* bias, const float* bias2,
                       float* Cf, short* Cb, short* Cb2,
                       int M, int N, int K, int ldc,
                       const float* rawq = nullptr, const float* resid = nullptr)
{
  dim3 g(M/64, N/64), blk(256);
  switch (epi) {
    case 0: gemm64<0><<<g,blk,0,st>>>(A,B,bias,bias2,Cf,Cb,Cb2,M,N,K,ldc,rawq,resid); break;
    case 1: gemm64<1><<<g,blk,0,st>>>(A,B,bias,bias2,Cf,Cb,Cb2,M,N,K,ldc,rawq,resid); break;
    case 2: gemm64<2><<<g,blk,0,st>>>(A,B,bias,bias2,Cf,Cb,Cb2,M,N,K,ldc,rawq,resid); break;
    default:gemm64<4><<<g,blk,0,st>>>(A,B,bias,bias2,Cf,Cb,Cb2,M,N,K,ldc,rawq,resid); break;
  }
}

extern "C" void kernel_launch(void* const* d_in, const int* in_sizes, int n_in,
                              void* d_out, int out_size, void* d_ws, size_t ws_size,
                              hipStream_t stream)
{
  const float* tgt    = (const float*)d_in[0];
  const float* seg    = (const float*)d_in[1];
  const float* dur    = (const float*)d_in[2];
  const float* src    = (const float*)d_in[3];
  const int*   tlens  = (const int*)d_in[4];
  const int*   lstart = (const int*)d_in[5];
  const float* valid  = (const float*)d_in[6];
  const unsigned char* pmask = (const unsigned char*)d_in[7];
  const float* grid_w0 = (const float*)d_in[8];
  const float* grid_b0 = (const float*)d_in[9];
  const float* grid_w1 = (const float*)d_in[10];
  const float* grid_b1 = (const float*)d_in[11];
  const float* qs_w0 = (const float*)d_in[12];
  const float* qs_b0 = (const float*)d_in[13];
  const float* qs_w1 = (const float*)d_in[14];
  const float* qs_b1 = (const float*)d_in[15];
  const float* sa_in_w  = (const float*)d_in[16];
  const float* sa_in_b  = (const float*)d_in[17];
  const float* sa_out_w = (const float*)d_in[18];
  const float* sa_out_b = (const float*)d_in[19];
  const float* n1_g = (const float*)d_in[20];
  const float* n1_b = (const float*)d_in[21];
  const float* n2_g = (const float*)d_in[22];
  const float* n2_b = (const float*)d_in[23];
  const float* n3_g = (const float*)d_in[24];
  const float* n3_b = (const float*)d_in[25];
  const float* off_w = (const float*)d_in[26];
  const float* off_b = (const float*)d_in[27];
  const float* aw_w  = (const float*)d_in[28];
  const float* aw_b  = (const float*)d_in[29];
  const float* val_w = (const float*)d_in[30];
  const float* val_b = (const float*)d_in[31];
  const float* outp_w = (const float*)d_in[32];
  const float* outp_b = (const float*)d_in[33];
  const float* ffn_w1 = (const float*)d_in[34];
  const float* ffn_b1 = (const float*)d_in[35];
  const float* ffn_w2 = (const float*)d_in[36];
  const float* ffn_b2 = (const float*)d_in[37];

  // bf16 weight region offsets (shorts); src bf16 follows weights
  const long W_G0=0, W_G1=131072, W_QS0=196608, W_QS1=262144, W_SAIN=327680,
             W_SAOUT=1507328, W_OFFAW=1900544, W_VAL=2195456,
             W_OUTP=2588672, W_FFN1=2981888, W_FFN2=4554752, W_SRC=6127616;

  char* ws = (char*)d_ws;
  short* wbf    = (short*)(ws + 0);
  short* srcbf  = wbf + W_SRC;
  short* sinebf = (short*)(ws + 70975488);
  short* ghbf   = (short*)(ws + 75890688);
  float* rawq   = (float*)(ws + 78348288);
  float* out    = (float*)(ws + 83263488);
  short* qbf    = (short*)(ws + 88178688);
  short* outbf  = qbf + (long)MROW*DM;
  short* t1bf   = (short*)(ws + 93093888);
  float* qpos   = (float*)(ws + 95551488);
  short* qkbf   = (short*)(ws + 100466688);   // [4800][512]
  short* vbf    = (short*)(ws + 105381888);   // [4800][256]
  short* attnbf = (short*)(ws + 107839488);
  float* tmpf   = (float*)(ws + 110297088);
  short* caqb   = (short*)(ws + 115212288);
  float* offaw  = (float*)(ws + 117669888);   // [4800][192]
  short* cabf   = (short*)(ws + 128729088);
  short* ffnhbf = (short*)(ws + 131186688);
  float* refin  = (float*)(ws + 141017088);
  short* valbf  = (short*)(ws + 141132288);   // [114688][256]

  CvtPtrs cp;
  cp.p[0]=grid_w0; cp.p[1]=grid_w1; cp.p[2]=qs_w0; cp.p[3]=qs_w1; cp.p[4]=sa_in_w;
  cp.p[5]=sa_out_w; cp.p[6]=off_w; cp.p[7]=aw_w; cp.p[8]=val_w; cp.p[9]=outp_w;
  cp.p[10]=ffn_w1; cp.p[11]=ffn_w2; cp.p[12]=src;
  cvt_all_kernel<<<dim3(34656), dim3(256), 0, stream>>>(cp, wbf);

  ew0_kernel<<<dim3(1200), dim3(256), 0, stream>>>(tgt, out, outbf);
  init_ref_kernel<<<dim3(MROW), dim3(256), 0, stream>>>(seg, dur, valid, sinebf, refin);

  g64(stream, 1, sinebf, wbf + W_G0, grid_b0, nullptr, nullptr, ghbf, nullptr, MROW, 256, 512, 256);
  g64(stream, 0, ghbf,   wbf + W_G1, grid_b1, nullptr, rawq, nullptr, nullptr, MROW, 256, 256, 256);

  for (int l = 0; l < NLAY; ++l) {
    // fused qs0(relu->t1bf) + v-proj(->vbf), same A=outbf
    gemm64_qs0v<<<dim3(75, 8), dim3(256), 0, stream>>>(
        outbf, wbf + W_QS0, wbf + W_SAIN + (long)l*196608 + 131072,
        qs_b0, sa_in_b + l*768 + 512, t1bf, vbf);
    g64(stream, 2, t1bf,  wbf + W_QS1, qs_b1, nullptr, qpos, qbf, nullptr, MROW, 256, 256, 256,
        rawq, out);
    g64(stream, 0, qbf, wbf + W_SAIN + (long)l*196608, sa_in_b + l*768, nullptr,
        nullptr, qkbf, nullptr, MROW, 512, 256, 512);
    attn_mfma<<<dim3(256), dim3(256), 0, stream>>>(qkbf, vbf, attnbf);
    g64(stream, 0, attnbf, wbf + W_SAOUT + (long)l*65536, sa_out_b + l*256, nullptr,
        tmpf, nullptr, nullptr, MROW, 256, 256, 256);
    ln4_kernel<<<dim3(MROW/4), dim3(256), 0, stream>>>(out, tmpf, n1_g + l*256, n1_b + l*256,
                                                       out, outbf, qpos, caqb);
    g64(stream, 4, caqb, wbf + W_OFFAW + (long)l*49152, off_b + l*96, aw_b + l*96,
        offaw, nullptr, nullptr, MROW, 192, 256, 192);
    val_gemm<<<dim3(448, 2), dim3(512), 0, stream>>>(
        srcbf, wbf + W_VAL + (long)l*65536, val_b + l*256, valbf, pmask);
    sample_kernel<<<dim3(MROW), dim3(256), 0, stream>>>(
        valbf, 256, offaw, refin, tlens, lstart, cabf);
    g64(stream, 0, cabf, wbf + W_OUTP + (long)l*65536, outp_b + l*256, nullptr,
        tmpf, nullptr, nullptr, MROW, 256, 256, 256);
    ln4_kernel<<<dim3(MROW/4), dim3(256), 0, stream>>>(out, tmpf, n2_g + l*256, n2_b + l*256,
                                                       out, outbf, nullptr, nullptr);
    g64(stream, 1, outbf, wbf + W_FFN1 + (long)l*262144, ffn_b1 + l*1024, nullptr,
        nullptr, ffnhbf, nullptr, MROW, 1024, 256, 1024);
    g64(stream, 0, ffnhbf, wbf + W_FFN2 + (long)l*262144, ffn_b2 + l*256, nullptr,
        tmpf, nullptr, nullptr, MROW, 256, 1024, 256);
    float* of = (l == NLAY-1) ? (float*)d_out : out;
    ln4_kernel<<<dim3(MROW/4), dim3(256), 0, stream>>>(out, tmpf, n3_g + l*256, n3_b + l*256,
                                                       of, outbf, nullptr, nullptr);
  }
}